// Round 6
// baseline (700.698 us; speedup 1.0000x reference)
//
#include <hip/hip_runtime.h>
#include <hip/hip_bf16.h>

typedef __hip_bfloat16 bf16;
typedef __attribute__((ext_vector_type(8))) short short8;
typedef __attribute__((ext_vector_type(4))) float f32x4;

#define NN   16
#define CIN  512
#define HH   56
#define WW   56
#define BB   (NN*WW)     /* 896 */
#define OO   1024
#define GG   8
#define RL   111         /* 2K-1 */
#define EPSV 1e-5f
#define NBATT 8          /* b-values per kScore/kAttn2 block */

// ---- shared LDS layout for kAttn2 (ushort offsets) ----
#define A2_QT  0         /* qT  [64 rows h][40u] cols c0..31          */
#define A2_KT  2560      /* kT  [64][40u]   (inputs end 5120)         */
#define A2_UL  0         /* Ul [56 i][112u d]  overlay after phase 2  */
#define A2_VL  6272      /* Vl [56][112u]      (end 12544)            */
#define A2_P   0         /* P  [64 i][72u j]   overlay after phase 4  */
#define A2_SP  4608      /* S' [64 i][136u d]  (end 13312)            */
#define A2_SIM 13312     /* sim f16 [56][60]   (end 16672)            */
#define A2_VH  13312     /* v half [32 c][72u j] phase 7 (SIM dead)   */
#define A2_TOT 16672     /* 33344 B -> 4 blocks/CU                    */

// relpad (ws) ushort offsets
#define RP_RQ 0          /* [112][40]  4480u */
#define RP_RK 4480       /* [112][40]  4480u */
#define RP_RV 8960       /* [64][136]  8704u  (end 17664) */

static __device__ __forceinline__ float u2f(unsigned short u){
  union { unsigned int i; float f; } x; x.i = ((unsigned int)u) << 16; return x.f;
}
static __device__ __forceinline__ unsigned short f2u(float f){
  union { float f; unsigned int i; } x; x.f = f;
  unsigned int i = x.i;
  unsigned int r = i + 0x7FFFu + ((i >> 16) & 1u);   // RNE
  return (unsigned short)(r >> 16);
}
static __device__ __forceinline__ float ldin(const void* p, size_t i, bool f32){
  return f32 ? ((const float*)p)[i] : u2f(((const unsigned short*)p)[i]);
}

typedef __attribute__((address_space(3))) unsigned int lds_u32;
typedef __attribute__((address_space(1))) const unsigned int glb_u32;

// ---------------- dtype probe + partial-stat zeroing ----------------
// zeroes st[2048 .. 7424): BN1/BN3 slot1 (sc3/sh3 region), sc2/sh2, flag,
// BN2 psum/psq, BN1/BN3 slot0.
__global__ void kDetect(const void* __restrict__ x, float* __restrict__ part, int* __restrict__ flag){
  const int t = threadIdx.x;     // 128 threads
  for (int i = t; i < 5376; i += 128) part[i] = 0.f;
  unsigned short u = ((const unsigned short*)x)[t];
  int e = (u >> 7) & 0xFF;
  int bad = (e < 100 || e > 140) ? 1 : 0;
  __shared__ int cnt;
  if (t == 0) cnt = 0;
  __syncthreads();
  if (bad) atomicAdd(&cnt, 1);
  __syncthreads();
  if (t == 0) *flag = (cnt > 16) ? 1 : 0;   // 1 => inputs are fp32
}

// ---------------- build padded/transposed rel images in ws (once) ----------------
__global__ __launch_bounds__(256) void kPrep(const void* __restrict__ rel, unsigned short* __restrict__ relpad,
                                             const int* __restrict__ dflag){
  const bool f32 = (*dflag != 0);
  const int t = threadIdx.x;
  for (int i = t; i < 8960; i += 256){          // RqT / RkT  [d][c]
    int reg = i / 4480, r = i - reg*4480;
    int d = r / 40, c = r - d*40;
    float v = (d < RL && c < 32) ? ldin(rel, (size_t)(reg*32 + c)*RL + d, f32) : 0.f;
    relpad[i] = f2u(v);
  }
  for (int i = t; i < 8704; i += 256){          // Rv [c][d]
    int c = i / 136, d = i - c*136;
    float v = (d < RL) ? ldin(rel, (size_t)(64 + c)*RL + d, f32) : 0.f;
    relpad[RP_RV + i] = f2u(v);
  }
}

// ---------------- pre-convert w_qkv to bf16 (once) ----------------
__global__ __launch_bounds__(256) void kWPrep(const void* __restrict__ w, unsigned short* __restrict__ wbf,
                                              const int* __restrict__ dflag){
  const bool f32 = (*dflag != 0);
  const size_t i = (size_t)blockIdx.x*256 + threadIdx.x;   // 2048*256 = 524288 = 1024*512
  wbf[i] = f2u(ldin(w, i, f32));
}

// ---------------- transpose x (N,C,H,W) -> xtk[b=(n*W+w)][h][c] ----------------
__global__ __launch_bounds__(256) void kTrans(const void* __restrict__ x, bf16* __restrict__ xtk,
                                              const int* __restrict__ dflag){
  const bool f32 = (*dflag != 0);
  const int h  = blockIdx.x;       // 56
  const int cg = blockIdx.y;       // 4 groups of 128 channels
  const int n  = blockIdx.z;       // 16
  __shared__ unsigned short tile[128][58];
  const size_t rbase = (((size_t)n*CIN + cg*128)*HH + h)*WW;
  if (f32){
    const float* xp = (const float*)x;
    for (int idx = threadIdx.x; idx < 128*14; idx += 256){
      int ci = idx / 14, w4 = idx - ci*14;
      float4 v = *(const float4*)(xp + rbase + (size_t)ci*HH*WW + w4*4);
      tile[ci][w4*4]   = f2u(v.x);
      tile[ci][w4*4+1] = f2u(v.y);
      tile[ci][w4*4+2] = f2u(v.z);
      tile[ci][w4*4+3] = f2u(v.w);
    }
  } else {
    for (int idx = threadIdx.x; idx < 128*WW; idx += 256){
      int ci = idx / WW, w = idx - ci*WW;
      tile[ci][w] = f2u(ldin(x, rbase + (size_t)ci*HH*WW + w, f32));
    }
  }
  __syncthreads();
  unsigned short* dst = (unsigned short*)xtk;
  for (int idx = threadIdx.x; idx < WW*16; idx += 256){
    int w = idx >> 4, c8 = idx & 15;
    short8 o;
    #pragma unroll
    for (int e = 0; e < 8; ++e) o[e] = (short)tile[c8*8+e][w];
    *(short8*)(dst + ((size_t)(n*WW + w)*HH + h)*CIN + cg*128 + c8*8) = o;
  }
}

// ---------------- MFMA GEMM: qkv[b][o][h] = sum_c w[o][c] * xtk[b][h][c] ----------------
__global__ __launch_bounds__(256) void kGemmQKV(const unsigned short* __restrict__ wbf,
                                                const bf16* __restrict__ xtk,
                                                bf16* __restrict__ qkv,
                                                float* __restrict__ pstats,
                                                float* __restrict__ pstatsB){
  // bijective XCD swizzle: each XCD gets 56 consecutive b-pairs x all 8 o-blocks
  const int id = blockIdx.x + (blockIdx.y << 3);      // grid (8,448)
  const int lb = (id & 7)*448 + (id >> 3);
  const int fo = lb & 7, fb = lb >> 3;
  const int o0 = fo * 128;
  const int b0 = fb * 2;
  const int t  = threadIdx.x;
  const int lane = t & 63, wv = t >> 6;
  const int q16 = lane >> 4, l16 = lane & 15;

  __shared__ __align__(16) unsigned short Bs[3][4096];   // [k8][128 cols][8]
  __shared__ __align__(16) unsigned short As[3][4096];   // [k8][128 rows][8]

  const int L1 = t, L2 = t + 256;
  const int k81 = L1 >> 7, j1 = L1 & 127;
  const int k82 = L2 >> 7, j2 = L2 & 127;
  const int je1 = (j1 < 112) ? j1 : 111;   // pad cols 112..127 (never consumed)
  const int je2 = (j2 < 112) ? j2 : 111;
  const int bs1 = (je1 >= 56), bs2 = (je2 >= 56);
  const unsigned short* pB1 = (const unsigned short*)xtk
      + ((size_t)(b0 + bs1)*HH + (je1 - 56*bs1))*CIN + k81*8;
  const unsigned short* pB2 = (const unsigned short*)xtk
      + ((size_t)(b0 + bs2)*HH + (je2 - 56*bs2))*CIN + k82*8;
  const unsigned short* pA1 = wbf + (size_t)(o0 + j1)*CIN + k81*8;
  const unsigned short* pA2 = wbf + (size_t)(o0 + j2)*CIN + k82*8;

  f32x4 acc[2][7];
  #pragma unroll
  for (int mt = 0; mt < 2; ++mt)
    #pragma unroll
    for (int nt = 0; nt < 7; ++nt) acc[mt][nt] = (f32x4){0.f,0.f,0.f,0.f};

#define GQ_STAGE(KK) do { \
    __builtin_amdgcn_global_load_lds((glb_u32*)(pB1 + (KK)*32), (lds_u32*)&Bs[(KK)%3][(size_t)L1*8], 16, 0, 0); \
    __builtin_amdgcn_global_load_lds((glb_u32*)(pB2 + (KK)*32), (lds_u32*)&Bs[(KK)%3][(size_t)L2*8], 16, 0, 0); \
    __builtin_amdgcn_global_load_lds((glb_u32*)(pA1 + (KK)*32), (lds_u32*)&As[(KK)%3][(size_t)L1*8], 16, 0, 0); \
    __builtin_amdgcn_global_load_lds((glb_u32*)(pA2 + (KK)*32), (lds_u32*)&As[(KK)%3][(size_t)L2*8], 16, 0, 0); \
  } while(0)

#define GQ_COMP(KK) do { \
    const int bi_ = (KK)%3; \
    const short8 ca0 = *(const short8*)&As[bi_][(q16*128 + wv*32 + l16)*8]; \
    const short8 ca1 = *(const short8*)&As[bi_][(q16*128 + wv*32 + 16 + l16)*8]; \
    _Pragma("unroll") \
    for (int nt = 0; nt < 7; ++nt){ \
      const short8 bfv = *(const short8*)&Bs[bi_][(q16*128 + nt*16 + l16)*8]; \
      acc[0][nt] = __builtin_amdgcn_mfma_f32_16x16x32_bf16(ca0, bfv, acc[0][nt], 0, 0, 0); \
      acc[1][nt] = __builtin_amdgcn_mfma_f32_16x16x32_bf16(ca1, bfv, acc[1][nt], 0, 0, 0); \
    } } while(0)

#define GQ_STEP(KK, WS) do { \
    asm volatile("s_waitcnt vmcnt(" WS ") lgkmcnt(0)" ::: "memory"); \
    __builtin_amdgcn_s_barrier(); \
    __builtin_amdgcn_sched_barrier(0); \
    if ((KK) <= 13) GQ_STAGE((KK)+2); \
    GQ_COMP(KK); \
  } while(0)

  GQ_STAGE(0); GQ_STAGE(1);
  GQ_STEP(0,"4");  GQ_STEP(1,"4");  GQ_STEP(2,"4");  GQ_STEP(3,"4");
  GQ_STEP(4,"4");  GQ_STEP(5,"4");  GQ_STEP(6,"4");  GQ_STEP(7,"4");
  GQ_STEP(8,"4");  GQ_STEP(9,"4");  GQ_STEP(10,"4"); GQ_STEP(11,"4");
  GQ_STEP(12,"4"); GQ_STEP(13,"4"); GQ_STEP(14,"4"); GQ_STEP(15,"0");

#undef GQ_STEP
#undef GQ_COMP
#undef GQ_STAGE

  // C-write
  unsigned short* dst = (unsigned short*)qkv;
  #pragma unroll
  for (int nt = 0; nt < 7; ++nt){
    const int j  = nt*16 + l16;
    const int bs = (j >= 56);
    const int h  = j - 56*bs;
    #pragma unroll
    for (int mt = 0; mt < 2; ++mt){
      const int orow = o0 + wv*32 + mt*16 + q16*4;
      size_t base = ((size_t)(b0 + bs)*OO + orow)*HH + h;
      #pragma unroll
      for (int r = 0; r < 4; ++r)
        dst[base + (size_t)r*HH] = f2u(acc[mt][nt][r]);
    }
  }

  // fused BN1 partial stats (f32 accs, pre-rounding); 2-slot spread by fb parity
  float* pa = (fb & 1) ? pstatsB : pstats;
  #pragma unroll
  for (int mt = 0; mt < 2; ++mt)
    #pragma unroll
    for (int r = 0; r < 4; ++r){
      float s = 0.f, q = 0.f;
      #pragma unroll
      for (int nt = 0; nt < 7; ++nt){ float v = acc[mt][nt][r]; s += v; q += v*v; }
      s += __shfl_xor(s, 1); q += __shfl_xor(q, 1);
      s += __shfl_xor(s, 2); q += __shfl_xor(q, 2);
      s += __shfl_xor(s, 4); q += __shfl_xor(q, 4);
      s += __shfl_xor(s, 8); q += __shfl_xor(q, 8);
      if (l16 == 0){
        const int row = o0 + wv*32 + mt*16 + q16*4 + r;
        atomicAdd(&pa[row], s);
        atomicAdd(&pa[1024 + row], q);
      }
    }
}

// ---------------- fold 2-slot partials -> scale/shift (BN1 & BN3), zero for reuse ----------------
__global__ void kFin(float* __restrict__ pst, float* __restrict__ pstB,
                     const void* __restrict__ gamma, const void* __restrict__ beta,
                     float* __restrict__ sc, float* __restrict__ sh, const int* __restrict__ dflag){
  const bool f32 = (*dflag != 0);
  const int ch = blockIdx.x*256 + threadIdx.x;   // grid 4 x 256 = 1024 channels
  float S = pst[ch] + pstB[ch];
  float Q = pst[1024 + ch] + pstB[1024 + ch];
  pst[ch] = 0.f; pst[1024 + ch] = 0.f;
  pstB[ch] = 0.f; pstB[1024 + ch] = 0.f;
  const float cnt = (float)(BB*HH);
  float mean = S / cnt;
  float var  = Q / cnt - mean*mean;
  float scale = ldin(gamma, ch, f32) * rsqrtf(var + EPSV);
  sc[ch] = scale; sh[ch] = ldin(beta, ch, f32) - mean*scale;
}

// ============ shared helpers ============
static __device__ __forceinline__ void stageQK(unsigned short* sm, const unsigned short* qkv,
                                               const float* __restrict__ sc1, const float* __restrict__ sh1,
                                               int b, int g, int t, bool zpad){
  const unsigned short* qp = qkv + (size_t)(b*OO + g*128)*HH;
  for (int q = t; q < 896; q += 256){           // q/k rows, ushort4
    int c = q / 14, hq = q - c*14;
    int o = g*128 + c;
    ushort4 u = *(const ushort4*)(qp + (size_t)c*HH + hq*4);
    float s = sc1[o], hb = sh1[o];
    int base = (c < 32 ? A2_QT : A2_KT) + (c & 31) + hq*160;
    sm[base]       = f2u(u2f(u.x)*s + hb);
    sm[base + 40]  = f2u(u2f(u.y)*s + hb);
    sm[base + 80]  = f2u(u2f(u.z)*s + hb);
    sm[base + 120] = f2u(u2f(u.w)*s + hb);
  }
  if (zpad){
    for (int i = t; i < 640; i += 256){         // zero rows 56..63 of qT/kT
      int a = i / 320, r = i - a*320;
      sm[(a ? A2_KT : A2_QT) + 2240 + r] = 0;
    }
  }
}

static __device__ __forceinline__ void scoreMFMA(const unsigned short* sm,
                                                 const unsigned short* __restrict__ relpad,
                                                 int w, int q16, int l16,
                                                 f32x4 aqk[4], f32x4 aU[7], f32x4 aV[7]){
  const short8 aq = *(const short8*)&sm[A2_QT + (w*16 + l16)*40 + q16*8];
  const short8 ak = *(const short8*)&sm[A2_KT + (w*16 + l16)*40 + q16*8];
  #pragma unroll
  for (int nt = 0; nt < 4; ++nt){
    const short8 bk = *(const short8*)&sm[A2_KT + (nt*16 + l16)*40 + q16*8];
    aqk[nt] = __builtin_amdgcn_mfma_f32_16x16x32_bf16(aq, bk, aqk[nt], 0, 0, 0);
  }
  #pragma unroll
  for (int nt = 0; nt < 7; ++nt){
    const short8 bq = *(const short8*)(relpad + RP_RQ + (nt*16 + l16)*40 + q16*8);
    const short8 br = *(const short8*)(relpad + RP_RK + (nt*16 + l16)*40 + q16*8);
    aU[nt] = __builtin_amdgcn_mfma_f32_16x16x32_bf16(aq, bq, aU[nt], 0, 0, 0);
    aV[nt] = __builtin_amdgcn_mfma_f32_16x16x32_bf16(ak, br, aV[nt], 0, 0, 0);
  }
}

static __device__ __forceinline__ void writeUV(unsigned short* sm, int w, int q16, int l16,
                                               const f32x4 aU[7], const f32x4 aV[7]){
  #pragma unroll
  for (int nt = 0; nt < 7; ++nt){
    const int d = nt*16 + l16;
    #pragma unroll
    for (int r = 0; r < 4; ++r){
      const int i = w*16 + q16*4 + r;
      if (i < HH){
        sm[A2_UL + i*112 + d] = f2u(aU[nt][r]);
        sm[A2_VL + i*112 + d] = f2u(aV[nt][r]);
      }
    }
  }
}

// ---------------- kScore: MFMA scores -> BN2 stats (8 b per block, reg accumulation) ----------------
__global__ __launch_bounds__(256) void kScore(const bf16* __restrict__ qkv,
                                              const unsigned short* __restrict__ relpad,
                                              const float* __restrict__ sc1, const float* __restrict__ sh1,
                                              float* __restrict__ psum, float* __restrict__ psq){
  const int b0 = blockIdx.x * NBATT, g = blockIdx.y;
  __shared__ __align__(16) unsigned short sm[5120];   // qT/kT only (10 KB)
  __shared__ float red[6][4];
  const int t = threadIdx.x;
  const int lane = t & 63, w = t >> 6;
  const int q16 = lane >> 4, l16 = lane & 15;

  float s0=0.f,s1=0.f,s2=0.f,p0=0.f,p1=0.f,p2=0.f;

  #pragma unroll 1
  for (int bi = 0; bi < NBATT; ++bi){
    stageQK(sm, (const unsigned short*)qkv, sc1, sh1, b0 + bi, g, t, bi == 0);
    __syncthreads();

    f32x4 aqk[4], aU[7], aV[7];
    #pragma unroll
    for (int nt = 0; nt < 4; ++nt) aqk[nt] = (f32x4){0.f,0.f,0.f,0.f};
    #pragma unroll
    for (int nt = 0; nt < 7; ++nt){ aU[nt] = (f32x4){0.f,0.f,0.f,0.f}; aV[nt] = (f32x4){0.f,0.f,0.f,0.f}; }
    scoreMFMA(sm, relpad, w, q16, l16, aqk, aU, aV);

    #pragma unroll
    for (int nt = 0; nt < 4; ++nt){
      const int j = nt*16 + l16;
      #pragma unroll
      for (int r = 0; r < 4; ++r){
        const int i = w*16 + q16*4 + r;
        if (i < HH && j < HH){ float v = aqk[nt][r]; s0 += v; p0 += v*v; }
      }
    }
    #pragma unroll
    for (int nt = 0; nt < 7; ++nt){
      const int d = nt*16 + l16;
      #pragma unroll
      for (int r = 0; r < 4; ++r){
        const int row = w*16 + q16*4 + r;
        if (row < HH && (unsigned)(d - row) < (unsigned)HH){
          float u = aU[nt][r]; s1 += u; p1 += u*u;
          float v = aV[nt][r]; s2 += v; p2 += v*v;
        }
      }
    }
    __syncthreads();   // MFMA LDS reads done before next stage overwrite
  }

  float s[3] = {s0,s1,s2}, q2[3] = {p0,p1,p2};
  #pragma unroll
  for (int off = 32; off > 0; off >>= 1)
    #pragma unroll
    for (int m = 0; m < 3; ++m){ s[m]+=__shfl_down(s[m],off); q2[m]+=__shfl_down(q2[m],off); }
  if ((t & 63) == 0){
    #pragma unroll
    for (int m = 0; m < 3; ++m){ red[m][w] = s[m]; red[3+m][w] = q2[m]; }
  }
  __syncthreads();
  if (t < 6){
    float v = red[t][0]+red[t][1]+red[t][2]+red[t][3];
    int m = t % 3;
    int ch = m*8 + g;
    float* dstp = (t >= 3) ? psq : psum;
    atomicAdd(&dstp[(blockIdx.x & 7)*24 + ch], v);    // 8-slot spread
  }
}

__global__ void kF2(const float* __restrict__ psum, const float* __restrict__ psq,
                    const void* __restrict__ gs, const void* __restrict__ bs,
                    float* __restrict__ sc2, float* __restrict__ sh2,
                    const int* __restrict__ dflag){
  const bool f32 = (*dflag != 0);
  const int ch = threadIdx.x;
  if (ch < 24){
    float S = 0.f, Q = 0.f;
    for (int sl = 0; sl < 8; ++sl){ S += psum[sl*24 + ch]; Q += psq[sl*24 + ch]; }
    const float cnt = (float)BB * (float)(HH*HH);
    float mean = S / cnt;
    float var  = Q / cnt - mean*mean;
    float scale = ldin(gs, ch, f32) * rsqrtf(var + EPSV);
    sc2[ch] = scale; sh2[ch] = ldin(bs, ch, f32) - mean*scale;
  }
}

// ---------------- kAttn2: scores -> BN2 -> softmax -> PV (8 b per block, fused BN3) ----------------
__global__ __launch_bounds__(256) void kAttn2(const bf16* __restrict__ qkv,
                                              const unsigned short* __restrict__ relpad,
                                              const float* __restrict__ sc1, const float* __restrict__ sh1,
                                              const float* __restrict__ sc2, const float* __restrict__ sh2,
                                              bf16* __restrict__ outr,
                                              float* __restrict__ pstats,
                                              float* __restrict__ pstatsB){
  const int b0 = blockIdx.x * NBATT, g = blockIdx.y;
  __shared__ __align__(16) unsigned short sm[A2_TOT];
  const int t = threadIdx.x;
  const int lane = t & 63, w = t >> 6;
  const int q16 = lane >> 4, l16 = lane & 15;
  const int i0 = w*16 + q16*4;
  const bool ivalid = (i0 < HH);

  const float scqk=sc2[g],    shqk=sh2[g];
  const float scqr=sc2[8+g],  shqr=sh2[8+g];
  const float sckr=sc2[16+g], shkr=sh2[16+g];

  float st3[4][4];   // per-nt {ssv,qsv,ssve,qsve}, accumulated across the 8 b's
  #pragma unroll
  for (int nt = 0; nt < 4; ++nt)
    #pragma unroll
    for (int v = 0; v < 4; ++v) st3[nt][v] = 0.f;

  #pragma unroll 1
  for (int bi = 0; bi < NBATT; ++bi){
    const int b = b0 + bi;

    // phase 1: q/k staging (zero pad rows only on first iteration)
    stageQK(sm, (const unsigned short*)qkv, sc1, sh1, b, g, t, bi == 0);
    __syncthreads();

    // phase 2: score MFMAs
    f32x4 aqk[4], aU[7], aV[7];
    #pragma unroll
    for (int nt = 0; nt < 4; ++nt) aqk[nt] = (f32x4){0.f,0.f,0.f,0.f};
    #pragma unroll
    for (int nt = 0; nt < 7; ++nt){ aU[nt] = (f32x4){0.f,0.f,0.f,0.f}; aV[nt] = (f32x4){0.f,0.f,0.f,0.f}; }
    scoreMFMA(sm, relpad, w, q16, l16, aqk, aU, aV);
    __syncthreads();

    // phase 3: Ul/Vl overlay
    writeUV(sm, w, q16, l16, aU, aV);
    __syncthreads();

    // phase 4: sim = BN2(qk)+BN2(qr)+BN2(kr), f16
    {
      _Float16* simh = (_Float16*)&sm[A2_SIM];
      #pragma unroll
      for (int nt = 0; nt < 4; ++nt){
        const int j = nt*16 + l16;
        #pragma unroll
        for (int r = 0; r < 4; ++r){
          const int i = w*16 + q16*4 + r;
          if (i < HH && j < HH){
            float qr = u2f(sm[A2_UL + i*112 + (i - j + 55)]);
            float kr = u2f(sm[A2_VL + j*112 + (j - i + 55)]);
            float sv_ = aqk[nt][r]*scqk + shqk + qr*scqr + shqr + kr*sckr + shkr;
            simh[i*60 + j] = (_Float16)sv_;
          }
        }
      }
    }
    __syncthreads();

    // phase 5: full zero of P/S' (13312u = 6656 dwords) — writeUV clobbers this
    // region every iteration, so the full zero + barrier is required every time.
    for (int i = t; i < 6656; i += 256) ((unsigned int*)sm)[i] = 0u;
    __syncthreads();

    // phase 6: softmax rows -> P and gathered S'
    if (t < 224){
      const _Float16* simh = (const _Float16*)&sm[A2_SIM];
      const int r = t >> 2, l4 = t & 3;
      float pvv[14]; float mx = -1e30f;
      #pragma unroll
      for (int m = 0; m < 14; ++m){ pvv[m] = (float)simh[r*60 + l4 + 4*m]; mx = fmaxf(mx, pvv[m]); }
      mx = fmaxf(mx, __shfl_xor(mx, 1)); mx = fmaxf(mx, __shfl_xor(mx, 2));
      float smm = 0.f;
      #pragma unroll
      for (int m = 0; m < 14; ++m){ pvv[m] = __expf(pvv[m] - mx); smm += pvv[m]; }
      smm += __shfl_xor(smm, 1); smm += __shfl_xor(smm, 2);
      const float inv = 1.f / smm;
      #pragma unroll
      for (int m = 0; m < 14; ++m){
        const int j = l4 + 4*m;
        unsigned short pu = f2u(pvv[m]*inv);
        sm[A2_P  + r*72  + j]            = pu;
        sm[A2_SP + r*136 + (r - j + 55)] = pu;
      }
    }
    __syncthreads();

    // phase 7: PV in two c-halves
    f32x4 asv[4], asve[4];
    #pragma unroll
    for (int nt = 0; nt < 4; ++nt){ asv[nt] = (f32x4){0.f,0.f,0.f,0.f}; asve[nt] = (f32x4){0.f,0.f,0.f,0.f}; }
    const short8 ap0 = *(const short8*)&sm[A2_P + (w*16 + l16)*72 + q16*8];
    const short8 ap1 = *(const short8*)&sm[A2_P + (w*16 + l16)*72 + 32 + q16*8];
    short8 asp[4];
    #pragma unroll
    for (int kk = 0; kk < 4; ++kk)
      asp[kk] = *(const short8*)&sm[A2_SP + (w*16 + l16)*136 + kk*32 + q16*8];

    #pragma unroll
    for (int half = 0; half < 2; ++half){
      const unsigned short* vp = (const unsigned short*)qkv
          + ((size_t)b*OO + g*128 + 64 + half*32)*HH;
      for (int q = t; q < 448; q += 256){
        int c2 = q / 14, hq = q - c2*14;
        int o = g*128 + 64 + half*32 + c2;
        ushort4 u = *(const ushort4*)(vp + (size_t)c2*HH + hq*4);
        float s = sc1[o], hb = sh1[o];
        unsigned short* d = &sm[A2_VH + c2*72 + hq*4];
        d[0] = f2u(u2f(u.x)*s + hb);
        d[1] = f2u(u2f(u.y)*s + hb);
        d[2] = f2u(u2f(u.z)*s + hb);
        d[3] = f2u(u2f(u.w)*s + hb);
      }
      { int c2 = t >> 3, e = t & 7; sm[A2_VH + c2*72 + 56 + e] = 0; }
      __syncthreads();
      #pragma unroll
      for (int ntl = 0; ntl < 2; ++ntl){
        const int nt = half*2 + ntl;
        const short8 bv0 = *(const short8*)&sm[A2_VH + (ntl*16 + l16)*72 + q16*8];
        const short8 bv1 = *(const short8*)&sm[A2_VH + (ntl*16 + l16)*72 + 32 + q16*8];
        asv[nt] = __builtin_amdgcn_mfma_f32_16x16x32_bf16(ap0, bv0, asv[nt], 0, 0, 0);
        asv[nt] = __builtin_amdgcn_mfma_f32_16x16x32_bf16(ap1, bv1, asv[nt], 0, 0, 0);
        #pragma unroll
        for (int kk = 0; kk < 4; ++kk){
          const short8 br = *(const short8*)(relpad + RP_RV
              + (size_t)(half*32 + ntl*16 + l16)*136 + kk*32 + q16*8);
          asve[nt] = __builtin_amdgcn_mfma_f32_16x16x32_bf16(asp[kk], br, asve[nt], 0, 0, 0);
        }
      }
      __syncthreads();
    }

    // C-write + BN3 accumulation (registers)
    if (ivalid){
      unsigned short* op = (unsigned short*)outr + (size_t)b*OO*HH;
      #pragma unroll
      for (int nt = 0; nt < 4; ++nt){
        const int c = nt*16 + l16;
        const int och = (g*64 + c)*2;
        *(ushort4*)(op + (size_t)och*HH + i0) =
          make_ushort4(f2u(asv[nt][0]),  f2u(asv[nt][1]),  f2u(asv[nt][2]),  f2u(asv[nt][3]));
        *(ushort4*)(op + (size_t)(och+1)*HH + i0) =
          make_ushort4(f2u(asve[nt][0]), f2u(asve[nt][1]), f2u(asve[nt][2]), f2u(asve[nt][3]));
        #pragma unroll
        for (int r = 0; r < 4; ++r){
          float a = asv[nt][r], e2 = asve[nt][r];
          st3[nt][0] += a;  st3[nt][1] += a*a;
          st3[nt][2] += e2; st3[nt][3] += e2*e2;
        }
      }
    }
  }

  // BN3 partial-stat reduce (once per block) -> 2-slot spread atomics
  {
    float* fr = (float*)sm;     // 1024 f32 = 4 KB scratch (all phases done)
    #pragma unroll
    for (int nt = 0; nt < 4; ++nt){
      float ssv = st3[nt][0], qsv = st3[nt][1], ssve = st3[nt][2], qsve = st3[nt][3];
      ssv  += __shfl_xor(ssv, 16);  ssv  += __shfl_xor(ssv, 32);
      qsv  += __shfl_xor(qsv, 16);  qsv  += __shfl_xor(qsv, 32);
      ssve += __shfl_xor(ssve, 16); ssve += __shfl_xor(ssve, 32);
      qsve += __shfl_xor(qsve, 16); qsve += __shfl_xor(qsve, 32);
      if (q16 == 0)
        *(f32x4*)&fr[(size_t)w*256 + (nt*16 + l16)*4] = (f32x4){ssv, qsv, ssve, qsve};
    }
    __syncthreads();
    float xv = fr[t] + fr[256 + t] + fr[512 + t] + fr[768 + t];
    const int nt = t >> 6, l16v = (t >> 2) & 15, v = t & 3;
    const int och = (g*64 + nt*16 + l16v)*2 + (v >> 1);
    float* pa = (blockIdx.x & 1) ? pstatsB : pstats;
    float* arr = (v & 1) ? (pa + 1024) : pa;
    atomicAdd(&arr[och], xv);
  }
}

// ---------------- BN3 + pair-sum + transpose to (N,512,H,W) ----------------
__global__ __launch_bounds__(256) void kOut(const bf16* __restrict__ outr, const float* __restrict__ sc3,
                                            const float* __restrict__ sh3, void* __restrict__ out,
                                            const int* __restrict__ dflag){
  const bool f32 = (*dflag != 0);
  const int p = blockIdx.x, n = blockIdx.y;
  __shared__ float tile[HH][WW+2];
  const unsigned short* ip = (const unsigned short*)outr;
  const float s0 = sc3[2*p], h0 = sh3[2*p], s1 = sc3[2*p+1], h1 = sh3[2*p+1];
  for (int idx = threadIdx.x; idx < 392; idx += 256){     // 56 w x 7 h-octs
    int w = idx / 7, h8 = idx - w*7;
    size_t base = ((size_t)((n*WW + w)*OO) + 2*p)*HH + h8*8;
    short8 ua = *(const short8*)(ip + base);
    short8 ub = *(const short8*)(ip + base + HH);
    #pragma unroll
    for (int e = 0; e < 8; ++e)
      tile[h8*8+e][w] = u2f((unsigned short)ua[e])*s0 + h0 + u2f((unsigned short)ub[e])*s1 + h1;
  }
  __syncthreads();
  const size_t obase = ((size_t)(n*512 + p))*HH*WW;
  for (int idx = threadIdx.x; idx < 784; idx += 256){     // 56 h x 14 w-quads
    int h = idx / 14, w4 = idx - h*14;
    float4 v = make_float4(tile[h][w4*4], tile[h][w4*4+1], tile[h][w4*4+2], tile[h][w4*4+3]);
    if (f32){
      *(float4*)((float*)out + obase + (size_t)h*WW + w4*4) = v;
    } else {
      *(ushort4*)((unsigned short*)out + obase + (size_t)h*WW + w4*4) =
        make_ushort4(f2u(v.x), f2u(v.y), f2u(v.z), f2u(v.w));
    }
  }
}

extern "C" void kernel_launch(void* const* d_in, const int* in_sizes, int n_in,
                              void* d_out, int out_size, void* d_ws, size_t ws_size,
                              hipStream_t stream){
  (void)in_sizes; (void)n_in; (void)out_size; (void)ws_size;
  const void* x    = d_in[0];
  const void* wqkv = d_in[1];
  const void* rel  = d_in[2];
  const void* gq   = d_in[3];
  const void* bq   = d_in[4];
  const void* gs   = d_in[5];
  const void* bs   = d_in[6];
  const void* go   = d_in[7];
  const void* bo   = d_in[8];

  char* ws = (char*)d_ws;
  const size_t szA = (size_t)BB*OO*HH*2;   // 102,760,448 B
  bf16* xtk  = (bf16*)ws;                  // [B][H][C]  (dead after GEMM)
  bf16* outr = (bf16*)ws;                  // [B][O][H]  (reuses region A)
  unsigned short* wbf = (unsigned short*)(ws + (size_t)64*1024*1024);   // 1 MB
  bf16* qkv  = (bf16*)(ws + szA);          // [B][O][H]
  float* st  = (float*)(ws + 2*szA);
  float* sc1   = st;
  float* sh1   = st + 1024;
  float* sc3   = st + 2048;                // doubles as BN1/BN3 pstats slot B (sum)
  float* sh3   = st + 3072;                // doubles as BN1/BN3 pstats slot B (sq)
  float* pstatsB = st + 2048;              // [1024] sum + [1024] sq
  float* sc2   = st + 4096;
  float* sh2   = st + 4128;
  int*   flag  = (int*)(st + 4160);
  // kDetect zeroes st[2048 .. 7424):
  float* psum   = st + 4352;               // BN2 [8][24]
  float* psq    = st + 4544;               // BN2 [8][24]
  float* pstats = st + 4736;               // BN1/BN3 slot A: [1024] sum + [1024] sq
  unsigned short* relpad = (unsigned short*)(ws + 2*szA + 32768);  // 17664u

  kDetect <<<1, 128, 0, stream>>>(x, st + 2048, flag);
  kPrep   <<<1, 256, 0, stream>>>(rel, relpad, flag);
  kWPrep  <<<2048, 256, 0, stream>>>(wqkv, wbf, flag);
  kTrans  <<<dim3(HH, 4, NN), 256, 0, stream>>>(x, xtk, flag);
  kGemmQKV<<<dim3(8, BB/2), 256, 0, stream>>>(wbf, xtk, qkv, pstats, pstatsB);
  kFin    <<<4, 256, 0, stream>>>(pstats, pstatsB, gq, bq, sc1, sh1, flag);
  kScore  <<<dim3(BB/NBATT, GG), 256, 0, stream>>>(qkv, relpad, sc1, sh1, psum, psq);
  kF2     <<<1, 64, 0, stream>>>(psum, psq, gs, bs, sc2, sh2, flag);
  kAttn2  <<<dim3(BB/NBATT, GG), 256, 0, stream>>>(qkv, relpad, sc1, sh1, sc2, sh2, outr, pstats, pstatsB);
  kFin    <<<4, 256, 0, stream>>>(pstats, pstatsB, go, bo, sc3, sh3, flag);
  kOut    <<<dim3(512, NN), 256, 0, stream>>>(outr, sc3, sh3, d_out, flag);
}

// Round 7
// 578.738 us; speedup vs baseline: 1.2107x; 1.2107x over previous
//
#include <hip/hip_runtime.h>
#include <hip/hip_bf16.h>

typedef __hip_bfloat16 bf16;
typedef __attribute__((ext_vector_type(8))) short short8;
typedef __attribute__((ext_vector_type(4))) float f32x4;

#define NN   16
#define CIN  512
#define HH   56
#define WW   56
#define BB   (NN*WW)     /* 896 */
#define OO   1024
#define GG   8
#define RL   111         /* 2K-1 */
#define EPSV 1e-5f

// ---- shared LDS layout for kAttn2 (ushort offsets) ----
#define A2_QT  0         /* qT  [64 rows h][40u] cols c0..31          */
#define A2_KT  2560      /* kT  [64][40u]   (inputs end 5120)         */
#define A2_UL  0         /* Ul [56 i][112u d]  overlay after phase 2  */
#define A2_VL  6272      /* Vl [56][112u]      (end 12544)            */
#define A2_P   0         /* P  [64 i][72u j]   overlay after phase 4  */
#define A2_SP  4608      /* S' [64 i][136u d]  (end 13312)            */
#define A2_SIM 13312     /* sim f16 [56][60]   (end 16672)            */
#define A2_VH  13312     /* v half [32 c][72u j] phase 7 (SIM dead)   */
#define A2_TOT 16672     /* 33344 B -> 4 blocks/CU                    */

// relpad (ws) ushort offsets
#define RP_RQ 0          /* [112][40]  4480u */
#define RP_RK 4480       /* [112][40]  4480u */
#define RP_RV 8960       /* [64][136]  8704u  (end 17664) */

static __device__ __forceinline__ float u2f(unsigned short u){
  union { unsigned int i; float f; } x; x.i = ((unsigned int)u) << 16; return x.f;
}
static __device__ __forceinline__ unsigned short f2u(float f){
  union { float f; unsigned int i; } x; x.f = f;
  unsigned int i = x.i;
  unsigned int r = i + 0x7FFFu + ((i >> 16) & 1u);   // RNE
  return (unsigned short)(r >> 16);
}
static __device__ __forceinline__ float ldin(const void* p, size_t i, bool f32){
  return f32 ? ((const float*)p)[i] : u2f(((const unsigned short*)p)[i]);
}

typedef __attribute__((address_space(3))) unsigned int lds_u32;
typedef __attribute__((address_space(1))) const unsigned int glb_u32;

// ---------------- dtype probe + BN2 partial-stat zeroing ----------------
__global__ void kDetect(const void* __restrict__ x, float* __restrict__ part, int* __restrict__ flag){
  const int t = threadIdx.x;     // 128 threads
  for (int i = t; i < 5376; i += 128) part[i] = 0.f;   // st[2048..7424)
  unsigned short u = ((const unsigned short*)x)[t];
  int e = (u >> 7) & 0xFF;
  int bad = (e < 100 || e > 140) ? 1 : 0;
  __shared__ int cnt;
  if (t == 0) cnt = 0;
  __syncthreads();
  if (bad) atomicAdd(&cnt, 1);
  __syncthreads();
  if (t == 0) *flag = (cnt > 16) ? 1 : 0;   // 1 => inputs are fp32
}

// ---------------- build padded/transposed rel images in ws (once) ----------------
__global__ __launch_bounds__(256) void kPrep(const void* __restrict__ rel, unsigned short* __restrict__ relpad,
                                             const int* __restrict__ dflag){
  const bool f32 = (*dflag != 0);
  const int t = threadIdx.x;
  for (int i = t; i < 8960; i += 256){          // RqT / RkT  [d][c]
    int reg = i / 4480, r = i - reg*4480;
    int d = r / 40, c = r - d*40;
    float v = (d < RL && c < 32) ? ldin(rel, (size_t)(reg*32 + c)*RL + d, f32) : 0.f;
    relpad[i] = f2u(v);
  }
  for (int i = t; i < 8704; i += 256){          // Rv [c][d]
    int c = i / 136, d = i - c*136;
    float v = (d < RL) ? ldin(rel, (size_t)(64 + c)*RL + d, f32) : 0.f;
    relpad[RP_RV + i] = f2u(v);
  }
}

// ---------------- pre-convert w_qkv to bf16 + zero pstG (once) ----------------
__global__ __launch_bounds__(256) void kWPrep(const void* __restrict__ w, unsigned short* __restrict__ wbf,
                                              float* __restrict__ pstG, const int* __restrict__ dflag){
  const bool f32 = (*dflag != 0);
  const size_t i = (size_t)blockIdx.x*256 + threadIdx.x;   // 2048*256 = 524288 = 1024*512
  wbf[i] = f2u(ldin(w, i, f32));
  if (blockIdx.x < 256){   // zero 256*256*4 = 262144 floats = pst1 + pst3 (1 MB)
    ((f32x4*)pstG)[(size_t)blockIdx.x*256 + threadIdx.x] = (f32x4){0.f,0.f,0.f,0.f};
  }
}

// ---------------- transpose x (N,C,H,W) -> xtk[b=(n*W+w)][h][c] ----------------
__global__ __launch_bounds__(256) void kTrans(const void* __restrict__ x, bf16* __restrict__ xtk,
                                              const int* __restrict__ dflag){
  const bool f32 = (*dflag != 0);
  const int h  = blockIdx.x;       // 56
  const int cg = blockIdx.y;       // 4 groups of 128 channels
  const int n  = blockIdx.z;       // 16
  __shared__ unsigned short tile[128][58];
  const size_t rbase = (((size_t)n*CIN + cg*128)*HH + h)*WW;
  if (f32){
    const float* xp = (const float*)x;
    for (int idx = threadIdx.x; idx < 128*14; idx += 256){
      int ci = idx / 14, w4 = idx - ci*14;
      float4 v = *(const float4*)(xp + rbase + (size_t)ci*HH*WW + w4*4);
      tile[ci][w4*4]   = f2u(v.x);
      tile[ci][w4*4+1] = f2u(v.y);
      tile[ci][w4*4+2] = f2u(v.z);
      tile[ci][w4*4+3] = f2u(v.w);
    }
  } else {
    for (int idx = threadIdx.x; idx < 128*WW; idx += 256){
      int ci = idx / WW, w = idx - ci*WW;
      tile[ci][w] = f2u(ldin(x, rbase + (size_t)ci*HH*WW + w, f32));
    }
  }
  __syncthreads();
  unsigned short* dst = (unsigned short*)xtk;
  for (int idx = threadIdx.x; idx < WW*16; idx += 256){
    int w = idx >> 4, c8 = idx & 15;
    short8 o;
    #pragma unroll
    for (int e = 0; e < 8; ++e) o[e] = (short)tile[c8*8+e][w];
    *(short8*)(dst + ((size_t)(n*WW + w)*HH + h)*CIN + cg*128 + c8*8) = o;
  }
}

// ---------------- MFMA GEMM: qkv[b][o][h] = sum_c w[o][c] * xtk[b][h][c] ----------------
// 3-deep counted-vmcnt global_load_lds pipeline, XCD-swizzled, BN1 partials -> pst1 (64-slot).
__global__ __launch_bounds__(256) void kGemmQKV(const unsigned short* __restrict__ wbf,
                                                const bf16* __restrict__ xtk,
                                                bf16* __restrict__ qkv,
                                                float* __restrict__ pst1){
  // bijective XCD swizzle: each XCD gets 56 consecutive b-pairs x all 8 o-blocks
  const int id = blockIdx.x + (blockIdx.y << 3);      // grid (8,448)
  const int lb = (id & 7)*448 + (id >> 3);
  const int fo = lb & 7, fb = lb >> 3;
  const int o0 = fo * 128;
  const int b0 = fb * 2;
  const int t  = threadIdx.x;
  const int lane = t & 63, wv = t >> 6;
  const int q16 = lane >> 4, l16 = lane & 15;

  __shared__ __align__(16) unsigned short Bs[3][4096];   // [k8][128 cols][8]
  __shared__ __align__(16) unsigned short As[3][4096];   // [k8][128 rows][8]

  const int L1 = t, L2 = t + 256;
  const int k81 = L1 >> 7, j1 = L1 & 127;
  const int k82 = L2 >> 7, j2 = L2 & 127;
  const int je1 = (j1 < 112) ? j1 : 111;   // pad cols 112..127 (never consumed)
  const int je2 = (j2 < 112) ? j2 : 111;
  const int bs1 = (je1 >= 56), bs2 = (je2 >= 56);
  const unsigned short* pB1 = (const unsigned short*)xtk
      + ((size_t)(b0 + bs1)*HH + (je1 - 56*bs1))*CIN + k81*8;
  const unsigned short* pB2 = (const unsigned short*)xtk
      + ((size_t)(b0 + bs2)*HH + (je2 - 56*bs2))*CIN + k82*8;
  const unsigned short* pA1 = wbf + (size_t)(o0 + j1)*CIN + k81*8;
  const unsigned short* pA2 = wbf + (size_t)(o0 + j2)*CIN + k82*8;

  f32x4 acc[2][7];
  #pragma unroll
  for (int mt = 0; mt < 2; ++mt)
    #pragma unroll
    for (int nt = 0; nt < 7; ++nt) acc[mt][nt] = (f32x4){0.f,0.f,0.f,0.f};

#define GQ_STAGE(KK) do { \
    __builtin_amdgcn_global_load_lds((glb_u32*)(pB1 + (KK)*32), (lds_u32*)&Bs[(KK)%3][(size_t)L1*8], 16, 0, 0); \
    __builtin_amdgcn_global_load_lds((glb_u32*)(pB2 + (KK)*32), (lds_u32*)&Bs[(KK)%3][(size_t)L2*8], 16, 0, 0); \
    __builtin_amdgcn_global_load_lds((glb_u32*)(pA1 + (KK)*32), (lds_u32*)&As[(KK)%3][(size_t)L1*8], 16, 0, 0); \
    __builtin_amdgcn_global_load_lds((glb_u32*)(pA2 + (KK)*32), (lds_u32*)&As[(KK)%3][(size_t)L2*8], 16, 0, 0); \
  } while(0)

#define GQ_COMP(KK) do { \
    const int bi_ = (KK)%3; \
    const short8 ca0 = *(const short8*)&As[bi_][(q16*128 + wv*32 + l16)*8]; \
    const short8 ca1 = *(const short8*)&As[bi_][(q16*128 + wv*32 + 16 + l16)*8]; \
    _Pragma("unroll") \
    for (int nt = 0; nt < 7; ++nt){ \
      const short8 bfv = *(const short8*)&Bs[bi_][(q16*128 + nt*16 + l16)*8]; \
      acc[0][nt] = __builtin_amdgcn_mfma_f32_16x16x32_bf16(ca0, bfv, acc[0][nt], 0, 0, 0); \
      acc[1][nt] = __builtin_amdgcn_mfma_f32_16x16x32_bf16(ca1, bfv, acc[1][nt], 0, 0, 0); \
    } } while(0)

#define GQ_STEP(KK, WS) do { \
    asm volatile("s_waitcnt vmcnt(" WS ") lgkmcnt(0)" ::: "memory"); \
    __builtin_amdgcn_s_barrier(); \
    __builtin_amdgcn_sched_barrier(0); \
    if ((KK) <= 13) GQ_STAGE((KK)+2); \
    GQ_COMP(KK); \
  } while(0)

  GQ_STAGE(0); GQ_STAGE(1);
  GQ_STEP(0,"4");  GQ_STEP(1,"4");  GQ_STEP(2,"4");  GQ_STEP(3,"4");
  GQ_STEP(4,"4");  GQ_STEP(5,"4");  GQ_STEP(6,"4");  GQ_STEP(7,"4");
  GQ_STEP(8,"4");  GQ_STEP(9,"4");  GQ_STEP(10,"4"); GQ_STEP(11,"4");
  GQ_STEP(12,"4"); GQ_STEP(13,"4"); GQ_STEP(14,"4"); GQ_STEP(15,"0");

#undef GQ_STEP
#undef GQ_COMP
#undef GQ_STAGE

  // C-write
  unsigned short* dst = (unsigned short*)qkv;
  #pragma unroll
  for (int nt = 0; nt < 7; ++nt){
    const int j  = nt*16 + l16;
    const int bs = (j >= 56);
    const int h  = j - 56*bs;
    #pragma unroll
    for (int mt = 0; mt < 2; ++mt){
      const int orow = o0 + wv*32 + mt*16 + q16*4;
      size_t base = ((size_t)(b0 + bs)*OO + orow)*HH + h;
      #pragma unroll
      for (int r = 0; r < 4; ++r)
        dst[base + (size_t)r*HH] = f2u(acc[mt][nt][r]);
    }
  }

  // fused BN1 partial stats (f32 accs, pre-rounding); all 112 j-cols are valid samples.
  // LDS scratch (Bs reuse) -> one 64-slot-spread atomic per thread (7 contenders/addr).
  __syncthreads();               // all MFMA LDS reads done before Bs reuse
  float* fb32 = (float*)Bs;      // 256 floats
  #pragma unroll
  for (int mt = 0; mt < 2; ++mt)
    #pragma unroll
    for (int r = 0; r < 4; ++r){
      float s = 0.f, q = 0.f;
      #pragma unroll
      for (int nt = 0; nt < 7; ++nt){ float v = acc[mt][nt][r]; s += v; q += v*v; }
      s += __shfl_xor(s, 1); q += __shfl_xor(q, 1);
      s += __shfl_xor(s, 2); q += __shfl_xor(q, 2);
      s += __shfl_xor(s, 4); q += __shfl_xor(q, 4);
      s += __shfl_xor(s, 8); q += __shfl_xor(q, 8);
      if (l16 == 0){
        const int rl = wv*32 + mt*16 + q16*4 + r;   // [0,128)
        fb32[rl*2]     = s;
        fb32[rl*2 + 1] = q;
      }
    }
  __syncthreads();
  atomicAdd(&pst1[(size_t)(fb & 63)*2048 + fo*256 + t], fb32[t]);
}

// ---------------- fold BN1 64-slot partials -> scale/shift ----------------
__global__ __launch_bounds__(256) void kFin1(const float* __restrict__ pst1,
                                             const void* __restrict__ gamma, const void* __restrict__ beta,
                                             float* __restrict__ sc, float* __restrict__ sh,
                                             const int* __restrict__ dflag){
  const bool f32 = (*dflag != 0);
  const int fo = blockIdx.x;     // 8 blocks
  const int t = threadIdx.x;
  float tot = 0.f;
  for (int s = 0; s < 64; ++s) tot += pst1[(size_t)s*2048 + fo*256 + t];
  __shared__ float sd[256];
  sd[t] = tot;                   // index t = rl*2 + stat
  __syncthreads();
  if (t < 128){
    float S = sd[t*2], Q = sd[t*2 + 1];
    const int ch = fo*128 + t;
    const float cnt = (float)(BB*HH);
    float mean = S / cnt;
    float var  = Q / cnt - mean*mean;
    float scale = ldin(gamma, ch, f32) * rsqrtf(var + EPSV);
    sc[ch] = scale; sh[ch] = ldin(beta, ch, f32) - mean*scale;
  }
}

// ============ shared helpers ============
static __device__ __forceinline__ void stageQK(unsigned short* sm, const unsigned short* qkv,
                                               const float* __restrict__ sc1, const float* __restrict__ sh1,
                                               int b, int g, int t){
  const unsigned short* qp = qkv + (size_t)(b*OO + g*128)*HH;
  for (int q = t; q < 896; q += 256){           // q/k rows, ushort4
    int c = q / 14, hq = q - c*14;
    int o = g*128 + c;
    ushort4 u = *(const ushort4*)(qp + (size_t)c*HH + hq*4);
    float s = sc1[o], hb = sh1[o];
    int base = (c < 32 ? A2_QT : A2_KT) + (c & 31) + hq*160;
    sm[base]       = f2u(u2f(u.x)*s + hb);
    sm[base + 40]  = f2u(u2f(u.y)*s + hb);
    sm[base + 80]  = f2u(u2f(u.z)*s + hb);
    sm[base + 120] = f2u(u2f(u.w)*s + hb);
  }
  for (int i = t; i < 640; i += 256){           // zero rows 56..63 of qT/kT
    int a = i / 320, r = i - a*320;
    sm[(a ? A2_KT : A2_QT) + 2240 + r] = 0;
  }
}

static __device__ __forceinline__ void scoreMFMA(const unsigned short* sm,
                                                 const unsigned short* __restrict__ relpad,
                                                 int w, int q16, int l16,
                                                 f32x4 aqk[4], f32x4 aU[7], f32x4 aV[7]){
  const short8 aq = *(const short8*)&sm[A2_QT + (w*16 + l16)*40 + q16*8];
  const short8 ak = *(const short8*)&sm[A2_KT + (w*16 + l16)*40 + q16*8];
  #pragma unroll
  for (int nt = 0; nt < 4; ++nt){
    const short8 bk = *(const short8*)&sm[A2_KT + (nt*16 + l16)*40 + q16*8];
    aqk[nt] = __builtin_amdgcn_mfma_f32_16x16x32_bf16(aq, bk, aqk[nt], 0, 0, 0);
  }
  #pragma unroll
  for (int nt = 0; nt < 7; ++nt){
    const short8 bq = *(const short8*)(relpad + RP_RQ + (nt*16 + l16)*40 + q16*8);
    const short8 br = *(const short8*)(relpad + RP_RK + (nt*16 + l16)*40 + q16*8);
    aU[nt] = __builtin_amdgcn_mfma_f32_16x16x32_bf16(aq, bq, aU[nt], 0, 0, 0);
    aV[nt] = __builtin_amdgcn_mfma_f32_16x16x32_bf16(ak, br, aV[nt], 0, 0, 0);
  }
}

static __device__ __forceinline__ void writeUV(unsigned short* sm, int w, int q16, int l16,
                                               const f32x4 aU[7], const f32x4 aV[7]){
  #pragma unroll
  for (int nt = 0; nt < 7; ++nt){
    const int d = nt*16 + l16;
    #pragma unroll
    for (int r = 0; r < 4; ++r){
      const int i = w*16 + q16*4 + r;
      if (i < HH){
        sm[A2_UL + i*112 + d] = f2u(aU[nt][r]);
        sm[A2_VL + i*112 + d] = f2u(aV[nt][r]);
      }
    }
  }
}

// ---------------- kScore: MFMA scores -> BN2 stats, all in registers ----------------
__global__ __launch_bounds__(256) void kScore(const bf16* __restrict__ qkv,
                                              const unsigned short* __restrict__ relpad,
                                              const float* __restrict__ sc1, const float* __restrict__ sh1,
                                              float* __restrict__ psum, float* __restrict__ psq){
  const int b = blockIdx.x, g = blockIdx.y;
  __shared__ __align__(16) unsigned short sm[5120];   // qT/kT only (10 KB)
  __shared__ float red[6][4];
  const int t = threadIdx.x;
  const int lane = t & 63, w = t >> 6;
  const int q16 = lane >> 4, l16 = lane & 15;

  stageQK(sm, (const unsigned short*)qkv, sc1, sh1, b, g, t);
  __syncthreads();

  f32x4 aqk[4], aU[7], aV[7];
  #pragma unroll
  for (int nt = 0; nt < 4; ++nt) aqk[nt] = (f32x4){0.f,0.f,0.f,0.f};
  #pragma unroll
  for (int nt = 0; nt < 7; ++nt){ aU[nt] = (f32x4){0.f,0.f,0.f,0.f}; aV[nt] = (f32x4){0.f,0.f,0.f,0.f}; }
  scoreMFMA(sm, relpad, w, q16, l16, aqk, aU, aV);

  float s0=0.f,s1=0.f,s2=0.f,p0=0.f,p1=0.f,p2=0.f;
  #pragma unroll
  for (int nt = 0; nt < 4; ++nt){
    const int j = nt*16 + l16;
    #pragma unroll
    for (int r = 0; r < 4; ++r){
      const int i = w*16 + q16*4 + r;
      if (i < HH && j < HH){ float v = aqk[nt][r]; s0 += v; p0 += v*v; }
    }
  }
  #pragma unroll
  for (int nt = 0; nt < 7; ++nt){
    const int d = nt*16 + l16;
    #pragma unroll
    for (int r = 0; r < 4; ++r){
      const int row = w*16 + q16*4 + r;
      if (row < HH && (unsigned)(d - row) < (unsigned)HH){
        float u = aU[nt][r]; s1 += u; p1 += u*u;
        float v = aV[nt][r]; s2 += v; p2 += v*v;
      }
    }
  }
  float s[3] = {s0,s1,s2}, q2[3] = {p0,p1,p2};
  #pragma unroll
  for (int off = 32; off > 0; off >>= 1)
    #pragma unroll
    for (int m = 0; m < 3; ++m){ s[m]+=__shfl_down(s[m],off); q2[m]+=__shfl_down(q2[m],off); }
  if ((t & 63) == 0){
    #pragma unroll
    for (int m = 0; m < 3; ++m){ red[m][w] = s[m]; red[3+m][w] = q2[m]; }
  }
  __syncthreads();
  if (t < 6){
    float v = red[t][0]+red[t][1]+red[t][2]+red[t][3];
    int m = t % 3;
    int ch = m*8 + g;
    float* dstp = (t >= 3) ? psq : psum;
    atomicAdd(&dstp[(b & 7)*24 + ch], v);    // 8-slot spread
  }
}

__global__ void kF2(const float* __restrict__ psum, const float* __restrict__ psq,
                    const void* __restrict__ gs, const void* __restrict__ bs,
                    float* __restrict__ sc2, float* __restrict__ sh2,
                    const int* __restrict__ dflag){
  const bool f32 = (*dflag != 0);
  const int ch = threadIdx.x;
  if (ch < 24){
    float S = 0.f, Q = 0.f;
    for (int sl = 0; sl < 8; ++sl){ S += psum[sl*24 + ch]; Q += psq[sl*24 + ch]; }
    const float cnt = (float)BB * (float)(HH*HH);
    float mean = S / cnt;
    float var  = Q / cnt - mean*mean;
    float scale = ldin(gs, ch, f32) * rsqrtf(var + EPSV);
    sc2[ch] = scale; sh2[ch] = ldin(bs, ch, f32) - mean*scale;
  }
}

// ---------------- kAttn2: scores -> BN2 -> softmax -> PV (BN3 partials -> pst3) ----------------
__global__ __launch_bounds__(256) void kAttn2(const bf16* __restrict__ qkv,
                                              const unsigned short* __restrict__ relpad,
                                              const float* __restrict__ sc1, const float* __restrict__ sh1,
                                              const float* __restrict__ sc2, const float* __restrict__ sh2,
                                              bf16* __restrict__ outr,
                                              float* __restrict__ pst3){
  const int b = blockIdx.x, g = blockIdx.y;
  __shared__ __align__(16) unsigned short sm[A2_TOT];
  const int t = threadIdx.x;
  const int lane = t & 63, w = t >> 6;
  const int q16 = lane >> 4, l16 = lane & 15;

  // phase 1: q/k staging only (rel stays in global/L1)
  stageQK(sm, (const unsigned short*)qkv, sc1, sh1, b, g, t);
  __syncthreads();

  // phase 2: score MFMAs
  f32x4 aqk[4], aU[7], aV[7];
  #pragma unroll
  for (int nt = 0; nt < 4; ++nt) aqk[nt] = (f32x4){0.f,0.f,0.f,0.f};
  #pragma unroll
  for (int nt = 0; nt < 7; ++nt){ aU[nt] = (f32x4){0.f,0.f,0.f,0.f}; aV[nt] = (f32x4){0.f,0.f,0.f,0.f}; }
  scoreMFMA(sm, relpad, w, q16, l16, aqk, aU, aV);
  __syncthreads();

  // phase 3: Ul/Vl overlay
  writeUV(sm, w, q16, l16, aU, aV);
  __syncthreads();

  // phase 4: sim = BN2(qk)+BN2(qr)+BN2(kr), f16
  {
    const float scqk=sc2[g],    shqk=sh2[g];
    const float scqr=sc2[8+g],  shqr=sh2[8+g];
    const float sckr=sc2[16+g], shkr=sh2[16+g];
    _Float16* simh = (_Float16*)&sm[A2_SIM];
    #pragma unroll
    for (int nt = 0; nt < 4; ++nt){
      const int j = nt*16 + l16;
      #pragma unroll
      for (int r = 0; r < 4; ++r){
        const int i = w*16 + q16*4 + r;
        if (i < HH && j < HH){
          float qr = u2f(sm[A2_UL + i*112 + (i - j + 55)]);
          float kr = u2f(sm[A2_VL + j*112 + (j - i + 55)]);
          float sv_ = aqk[nt][r]*scqk + shqk + qr*scqr + shqr + kr*sckr + shkr;
          simh[i*60 + j] = (_Float16)sv_;
        }
      }
    }
  }
  __syncthreads();

  // phase 5: zero P/S' (13312u = 6656 dwords)
  for (int i = t; i < 6656; i += 256) ((unsigned int*)sm)[i] = 0u;
  __syncthreads();

  // phase 6: softmax rows -> P and gathered S'
  if (t < 224){
    const _Float16* simh = (const _Float16*)&sm[A2_SIM];
    const int r = t >> 2, l4 = t & 3;
    float pvv[14]; float mx = -1e30f;
    #pragma unroll
    for (int m = 0; m < 14; ++m){ pvv[m] = (float)simh[r*60 + l4 + 4*m]; mx = fmaxf(mx, pvv[m]); }
    mx = fmaxf(mx, __shfl_xor(mx, 1)); mx = fmaxf(mx, __shfl_xor(mx, 2));
    float smm = 0.f;
    #pragma unroll
    for (int m = 0; m < 14; ++m){ pvv[m] = __expf(pvv[m] - mx); smm += pvv[m]; }
    smm += __shfl_xor(smm, 1); smm += __shfl_xor(smm, 2);
    const float inv = 1.f / smm;
    #pragma unroll
    for (int m = 0; m < 14; ++m){
      const int j = l4 + 4*m;
      unsigned short pu = f2u(pvv[m]*inv);
      sm[A2_P  + r*72  + j]            = pu;
      sm[A2_SP + r*136 + (r - j + 55)] = pu;
    }
  }
  __syncthreads();

  // phase 7: PV in two c-halves (v staged into dead sim region; Rv read direct)
  f32x4 asv[4], asve[4];
  #pragma unroll
  for (int nt = 0; nt < 4; ++nt){ asv[nt] = (f32x4){0.f,0.f,0.f,0.f}; asve[nt] = (f32x4){0.f,0.f,0.f,0.f}; }
  const short8 ap0 = *(const short8*)&sm[A2_P + (w*16 + l16)*72 + q16*8];
  const short8 ap1 = *(const short8*)&sm[A2_P + (w*16 + l16)*72 + 32 + q16*8];
  short8 asp[4];
  #pragma unroll
  for (int kk = 0; kk < 4; ++kk)
    asp[kk] = *(const short8*)&sm[A2_SP + (w*16 + l16)*136 + kk*32 + q16*8];

  #pragma unroll
  for (int half = 0; half < 2; ++half){
    const unsigned short* vp = (const unsigned short*)qkv
        + ((size_t)b*OO + g*128 + 64 + half*32)*HH;
    for (int q = t; q < 448; q += 256){
      int c2 = q / 14, hq = q - c2*14;
      int o = g*128 + 64 + half*32 + c2;
      ushort4 u = *(const ushort4*)(vp + (size_t)c2*HH + hq*4);
      float s = sc1[o], hb = sh1[o];
      unsigned short* d = &sm[A2_VH + c2*72 + hq*4];
      d[0] = f2u(u2f(u.x)*s + hb);
      d[1] = f2u(u2f(u.y)*s + hb);
      d[2] = f2u(u2f(u.z)*s + hb);
      d[3] = f2u(u2f(u.w)*s + hb);
    }
    { int c2 = t >> 3, e = t & 7; sm[A2_VH + c2*72 + 56 + e] = 0; }
    __syncthreads();
    #pragma unroll
    for (int ntl = 0; ntl < 2; ++ntl){
      const int nt = half*2 + ntl;
      const short8 bv0 = *(const short8*)&sm[A2_VH + (ntl*16 + l16)*72 + q16*8];
      const short8 bv1 = *(const short8*)&sm[A2_VH + (ntl*16 + l16)*72 + 32 + q16*8];
      asv[nt] = __builtin_amdgcn_mfma_f32_16x16x32_bf16(ap0, bv0, asv[nt], 0, 0, 0);
      asv[nt] = __builtin_amdgcn_mfma_f32_16x16x32_bf16(ap1, bv1, asv[nt], 0, 0, 0);
      #pragma unroll
      for (int kk = 0; kk < 4; ++kk){
        const short8 br = *(const short8*)(relpad + RP_RV
            + (size_t)(half*32 + ntl*16 + l16)*136 + kk*32 + q16*8);
        asve[nt] = __builtin_amdgcn_mfma_f32_16x16x32_bf16(asp[kk], br, asve[nt], 0, 0, 0);
      }
    }
    __syncthreads();
  }

  // epilogue: C-write
  const int i0 = w*16 + q16*4;
  if (i0 < HH){
    unsigned short* op = (unsigned short*)outr + (size_t)b*OO*HH;
    #pragma unroll
    for (int nt = 0; nt < 4; ++nt){
      const int c = nt*16 + l16;
      const int och = (g*64 + c)*2;
      *(ushort4*)(op + (size_t)och*HH + i0) =
        make_ushort4(f2u(asv[nt][0]),  f2u(asv[nt][1]),  f2u(asv[nt][2]),  f2u(asv[nt][3]));
      *(ushort4*)(op + (size_t)(och+1)*HH + i0) =
        make_ushort4(f2u(asve[nt][0]), f2u(asve[nt][1]), f2u(asve[nt][2]), f2u(asve[nt][3]));
    }
  }

  // fused BN3 partial stats -> 64-slot-spread (14 contenders/addr)
  {
    float* fr = (float*)sm;
    const bool ivalid = (i0 < HH);
    #pragma unroll
    for (int nt = 0; nt < 4; ++nt){
      float ssv = 0.f, qsv = 0.f, ssve = 0.f, qsve = 0.f;
      if (ivalid){
        #pragma unroll
        for (int r = 0; r < 4; ++r){
          float a = asv[nt][r], e2 = asve[nt][r];
          ssv += a; qsv += a*a; ssve += e2; qsve += e2*e2;
        }
      }
      ssv  += __shfl_xor(ssv, 16);  ssv  += __shfl_xor(ssv, 32);
      qsv  += __shfl_xor(qsv, 16);  qsv  += __shfl_xor(qsv, 32);
      ssve += __shfl_xor(ssve, 16); ssve += __shfl_xor(ssve, 32);
      qsve += __shfl_xor(qsve, 16); qsve += __shfl_xor(qsve, 32);
      if (q16 == 0)
        *(f32x4*)&fr[(size_t)w*256 + (nt*16 + l16)*4] = (f32x4){ssv, qsv, ssve, qsve};
    }
    __syncthreads();
    float xv = fr[t] + fr[256 + t] + fr[512 + t] + fr[768 + t];
    atomicAdd(&pst3[(size_t)(b & 63)*2048 + g*256 + t], xv);
  }
}

// ---------------- fold BN3 64-slot partials -> scale/shift ----------------
__global__ __launch_bounds__(256) void kFin3(const float* __restrict__ pst3,
                                             const void* __restrict__ gamma, const void* __restrict__ beta,
                                             float* __restrict__ sc, float* __restrict__ sh,
                                             const int* __restrict__ dflag){
  const bool f32 = (*dflag != 0);
  const int g = blockIdx.x;      // 8 blocks
  const int t = threadIdx.x;
  float tot = 0.f;
  for (int s = 0; s < 64; ++s) tot += pst3[(size_t)s*2048 + g*256 + t];
  // t encodes: v=t&3, nt=t>>6, l16v=(t>>2)&15 -> och_local=(nt*16+l16v)*2+(v>>1), stat=v&1
  __shared__ float sd[256];
  const int v = t & 3, nt = t >> 6, l16v = (t >> 2) & 15;
  const int ol = (nt*16 + l16v)*2 + (v >> 1);
  sd[ol*2 + (v & 1)] = tot;
  __syncthreads();
  if (t < 128){
    float S = sd[t*2], Q = sd[t*2 + 1];
    const int ch = g*128 + t;
    const float cnt = (float)(BB*HH);
    float mean = S / cnt;
    float var  = Q / cnt - mean*mean;
    float scale = ldin(gamma, ch, f32) * rsqrtf(var + EPSV);
    sc[ch] = scale; sh[ch] = ldin(beta, ch, f32) - mean*scale;
  }
}

// ---------------- BN3 + pair-sum + transpose to (N,512,H,W) ----------------
__global__ __launch_bounds__(256) void kOut(const bf16* __restrict__ outr, const float* __restrict__ sc3,
                                            const float* __restrict__ sh3, void* __restrict__ out,
                                            const int* __restrict__ dflag){
  const bool f32 = (*dflag != 0);
  const int p = blockIdx.x, n = blockIdx.y;
  __shared__ float tile[HH][WW+2];
  const unsigned short* ip = (const unsigned short*)outr;
  const float s0 = sc3[2*p], h0 = sh3[2*p], s1 = sc3[2*p+1], h1 = sh3[2*p+1];
  for (int idx = threadIdx.x; idx < 392; idx += 256){     // 56 w x 7 h-octs
    int w = idx / 7, h8 = idx - w*7;
    size_t base = ((size_t)((n*WW + w)*OO) + 2*p)*HH + h8*8;
    short8 ua = *(const short8*)(ip + base);
    short8 ub = *(const short8*)(ip + base + HH);
    #pragma unroll
    for (int e = 0; e < 8; ++e)
      tile[h8*8+e][w] = u2f((unsigned short)ua[e])*s0 + h0 + u2f((unsigned short)ub[e])*s1 + h1;
  }
  __syncthreads();
  const size_t obase = ((size_t)(n*512 + p))*HH*WW;
  for (int idx = threadIdx.x; idx < 784; idx += 256){     // 56 h x 14 w-quads
    int h = idx / 14, w4 = idx - h*14;
    float4 v = make_float4(tile[h][w4*4], tile[h][w4*4+1], tile[h][w4*4+2], tile[h][w4*4+3]);
    if (f32){
      *(float4*)((float*)out + obase + (size_t)h*WW + w4*4) = v;
    } else {
      *(ushort4*)((unsigned short*)out + obase + (size_t)h*WW + w4*4) =
        make_ushort4(f2u(v.x), f2u(v.y), f2u(v.z), f2u(v.w));
    }
  }
}

extern "C" void kernel_launch(void* const* d_in, const int* in_sizes, int n_in,
                              void* d_out, int out_size, void* d_ws, size_t ws_size,
                              hipStream_t stream){
  (void)in_sizes; (void)n_in; (void)out_size; (void)ws_size;
  const void* x    = d_in[0];
  const void* wqkv = d_in[1];
  const void* rel  = d_in[2];
  const void* gq   = d_in[3];
  const void* bq   = d_in[4];
  const void* gs   = d_in[5];
  const void* bs   = d_in[6];
  const void* go   = d_in[7];
  const void* bo   = d_in[8];

  char* ws = (char*)d_ws;
  const size_t szA = (size_t)BB*OO*HH*2;   // 102,760,448 B
  bf16* xtk  = (bf16*)ws;                  // [B][H][C]  (dead after GEMM)
  bf16* outr = (bf16*)ws;                  // [B][O][H]  (reuses region A)
  unsigned short* wbf = (unsigned short*)(ws + (size_t)64*1024*1024);   // 1 MB
  bf16* qkv  = (bf16*)(ws + szA);          // [B][O][H]
  float* st  = (float*)(ws + 2*szA);
  float* sc1   = st;
  float* sh1   = st + 1024;
  float* sc3   = st + 2048;
  float* sh3   = st + 3072;
  float* sc2   = st + 4096;
  float* sh2   = st + 4128;
  int*   flag  = (int*)(st + 4160);
  // kDetect zeroes st[2048 .. 7424):
  float* psum   = st + 4352;               // BN2 [8][24]
  float* psq    = st + 4544;               // BN2 [8][24]
  unsigned short* relpad = (unsigned short*)(ws + 2*szA + 32768);  // 17664u, ends +68096
  float* pstG = (float*)(ws + 2*szA + 69632);   // 1 MB: pst1 [64][2048] + pst3 [64][2048]
  float* pst1 = pstG;
  float* pst3 = pstG + 131072;

  kDetect <<<1, 128, 0, stream>>>(x, st + 2048, flag);
  kPrep   <<<1, 256, 0, stream>>>(rel, relpad, flag);
  kWPrep  <<<2048, 256, 0, stream>>>(wqkv, wbf, pstG, flag);
  kTrans  <<<dim3(HH, 4, NN), 256, 0, stream>>>(x, xtk, flag);
  kGemmQKV<<<dim3(8, BB/2), 256, 0, stream>>>(wbf, xtk, qkv, pst1);
  kFin1   <<<8, 256, 0, stream>>>(pst1, gq, bq, sc1, sh1, flag);
  kScore  <<<dim3(BB, GG), 256, 0, stream>>>(qkv, relpad, sc1, sh1, psum, psq);
  kF2     <<<1, 64, 0, stream>>>(psum, psq, gs, bs, sc2, sh2, flag);
  kAttn2  <<<dim3(BB, GG), 256, 0, stream>>>(qkv, relpad, sc1, sh1, sc2, sh2, outr, pst3);
  kFin3   <<<8, 256, 0, stream>>>(pst3, go, bo, sc3, sh3, flag);
  kOut    <<<dim3(512, NN), 256, 0, stream>>>(outr, sc3, sh3, d_out, flag);
}

// Round 8
// 572.009 us; speedup vs baseline: 1.2250x; 1.0118x over previous
//
#include <hip/hip_runtime.h>
#include <hip/hip_bf16.h>

typedef __hip_bfloat16 bf16;
typedef __attribute__((ext_vector_type(8))) short short8;
typedef __attribute__((ext_vector_type(4))) float f32x4;

#define NN   16
#define CIN  512
#define HH   56
#define WW   56
#define BB   (NN*WW)     /* 896 */
#define OO   1024
#define GG   8
#define RL   111         /* 2K-1 */
#define EPSV 1e-5f

// ---- shared LDS layout for kAttn2 (ushort offsets) ----
#define A2_QT  0         /* qT  [64 rows h][40u] cols c0..31          */
#define A2_KT  2560      /* kT  [64][40u]   (inputs end 5120)         */
#define A2_UL  0         /* Ul [56 i][116u d] (stride 116: bank-clean)*/
#define A2_VL  6496      /* Vl [56][116u]     (end 12992)             */
#define A2_P   0         /* P  [64 i][72u j]   overlay after phase 4  */
#define A2_SP  4608      /* S' [64 i][136u d]  (end 13312)            */
#define A2_SIM 13312     /* sim f16 [56][60]   (end 16672)            */
#define A2_VH  13312     /* v half [32 c][72u j] phase 7 (SIM dead)   */
#define A2_TOT 16672     /* 33344 B -> 4 blocks/CU                    */

// relpad (ws) ushort offsets
#define RP_RQ 0          /* [112][40]  4480u */
#define RP_RK 4480       /* [112][40]  4480u */
#define RP_RV 8960       /* [64][136]  8704u  (end 17664) */

static __device__ __forceinline__ float u2f(unsigned short u){
  union { unsigned int i; float f; } x; x.i = ((unsigned int)u) << 16; return x.f;
}
static __device__ __forceinline__ unsigned short f2u(float f){
  union { float f; unsigned int i; } x; x.f = f;
  unsigned int i = x.i;
  unsigned int r = i + 0x7FFFu + ((i >> 16) & 1u);   // RNE
  return (unsigned short)(r >> 16);
}
static __device__ __forceinline__ float ldin(const void* p, size_t i, bool f32){
  return f32 ? ((const float*)p)[i] : u2f(((const unsigned short*)p)[i]);
}

typedef __attribute__((address_space(3))) unsigned int lds_u32;
typedef __attribute__((address_space(1))) const unsigned int glb_u32;

// ---------------- dtype probe + BN2 partial-stat zeroing ----------------
__global__ void kDetect(const void* __restrict__ x, float* __restrict__ part, int* __restrict__ flag){
  const int t = threadIdx.x;     // 128 threads
  for (int i = t; i < 5376; i += 128) part[i] = 0.f;   // st[2048..7424)
  unsigned short u = ((const unsigned short*)x)[t];
  int e = (u >> 7) & 0xFF;
  int bad = (e < 100 || e > 140) ? 1 : 0;
  __shared__ int cnt;
  if (t == 0) cnt = 0;
  __syncthreads();
  if (bad) atomicAdd(&cnt, 1);
  __syncthreads();
  if (t == 0) *flag = (cnt > 16) ? 1 : 0;   // 1 => inputs are fp32
}

// ---------------- build padded/transposed rel images in ws (once) ----------------
__global__ __launch_bounds__(256) void kPrep(const void* __restrict__ rel, unsigned short* __restrict__ relpad,
                                             const int* __restrict__ dflag){
  const bool f32 = (*dflag != 0);
  const int t = threadIdx.x;
  for (int i = t; i < 8960; i += 256){          // RqT / RkT  [d][c]
    int reg = i / 4480, r = i - reg*4480;
    int d = r / 40, c = r - d*40;
    float v = (d < RL && c < 32) ? ldin(rel, (size_t)(reg*32 + c)*RL + d, f32) : 0.f;
    relpad[i] = f2u(v);
  }
  for (int i = t; i < 8704; i += 256){          // Rv [c][d]
    int c = i / 136, d = i - c*136;
    float v = (d < RL) ? ldin(rel, (size_t)(64 + c)*RL + d, f32) : 0.f;
    relpad[RP_RV + i] = f2u(v);
  }
}

// ---------------- pre-convert w_qkv to bf16 + zero pstG (once) ----------------
__global__ __launch_bounds__(256) void kWPrep(const void* __restrict__ w, unsigned short* __restrict__ wbf,
                                              float* __restrict__ pstG, const int* __restrict__ dflag){
  const bool f32 = (*dflag != 0);
  const size_t i = (size_t)blockIdx.x*256 + threadIdx.x;   // 2048*256 = 524288 = 1024*512
  wbf[i] = f2u(ldin(w, i, f32));
  if (blockIdx.x < 256){   // zero 256*256*4 = 262144 floats = pst1 + pst3 (1 MB)
    ((f32x4*)pstG)[(size_t)blockIdx.x*256 + threadIdx.x] = (f32x4){0.f,0.f,0.f,0.f};
  }
}

// ---------------- transpose x (N,C,H,W) -> xtk[b=(n*W+w)][h][c] ----------------
__global__ __launch_bounds__(256) void kTrans(const void* __restrict__ x, bf16* __restrict__ xtk,
                                              const int* __restrict__ dflag){
  const bool f32 = (*dflag != 0);
  const int h  = blockIdx.x;       // 56
  const int cg = blockIdx.y;       // 4 groups of 128 channels
  const int n  = blockIdx.z;       // 16
  __shared__ unsigned short tile[128][58];
  const size_t rbase = (((size_t)n*CIN + cg*128)*HH + h)*WW;
  if (f32){
    const float* xp = (const float*)x;
    for (int idx = threadIdx.x; idx < 128*14; idx += 256){
      int ci = idx / 14, w4 = idx - ci*14;
      float4 v = *(const float4*)(xp + rbase + (size_t)ci*HH*WW + w4*4);
      tile[ci][w4*4]   = f2u(v.x);
      tile[ci][w4*4+1] = f2u(v.y);
      tile[ci][w4*4+2] = f2u(v.z);
      tile[ci][w4*4+3] = f2u(v.w);
    }
  } else {
    for (int idx = threadIdx.x; idx < 128*WW; idx += 256){
      int ci = idx / WW, w = idx - ci*WW;
      tile[ci][w] = f2u(ldin(x, rbase + (size_t)ci*HH*WW + w, f32));
    }
  }
  __syncthreads();
  unsigned short* dst = (unsigned short*)xtk;
  for (int idx = threadIdx.x; idx < WW*16; idx += 256){
    int w = idx >> 4, c8 = idx & 15;
    short8 o;
    #pragma unroll
    for (int e = 0; e < 8; ++e) o[e] = (short)tile[c8*8+e][w];
    *(short8*)(dst + ((size_t)(n*WW + w)*HH + h)*CIN + cg*128 + c8*8) = o;
  }
}

// ---------------- MFMA GEMM: qkv[b][o][h] = sum_c w[o][c] * xtk[b][h][c] ----------------
// B: 3-deep counted-vmcnt global_load_lds; A: register prefetch from L2-hot wbf.
// LDS 24 KB -> ~6 blocks/CU.
__global__ __launch_bounds__(256) void kGemmQKV(const unsigned short* __restrict__ wbf,
                                                const bf16* __restrict__ xtk,
                                                bf16* __restrict__ qkv,
                                                float* __restrict__ pst1){
  // bijective XCD swizzle: each XCD gets 56 consecutive b-pairs x all 8 o-blocks
  const int id = blockIdx.x + (blockIdx.y << 3);      // grid (8,448)
  const int lb = (id & 7)*448 + (id >> 3);
  const int fo = lb & 7, fb = lb >> 3;
  const int o0 = fo * 128;
  const int b0 = fb * 2;
  const int t  = threadIdx.x;
  const int lane = t & 63, wv = t >> 6;
  const int q16 = lane >> 4, l16 = lane & 15;

  __shared__ __align__(16) unsigned short Bs[3][4096];   // [k8][128 cols][8]

  const int L1 = t, L2 = t + 256;
  const int k81 = L1 >> 7, j1 = L1 & 127;
  const int k82 = L2 >> 7, j2 = L2 & 127;
  const int je1 = (j1 < 112) ? j1 : 111;   // pad cols 112..127 (never consumed)
  const int je2 = (j2 < 112) ? j2 : 111;
  const int bs1 = (je1 >= 56), bs2 = (je2 >= 56);
  const unsigned short* pB1 = (const unsigned short*)xtk
      + ((size_t)(b0 + bs1)*HH + (je1 - 56*bs1))*CIN + k81*8;
  const unsigned short* pB2 = (const unsigned short*)xtk
      + ((size_t)(b0 + bs2)*HH + (je2 - 56*bs2))*CIN + k82*8;
  const size_t aofs0 = (size_t)(o0 + wv*32 + l16)*CIN + q16*8;
  const size_t aofs1 = aofs0 + (size_t)16*CIN;

  f32x4 acc[2][7];
  #pragma unroll
  for (int mt = 0; mt < 2; ++mt)
    #pragma unroll
    for (int nt = 0; nt < 7; ++nt) acc[mt][nt] = (f32x4){0.f,0.f,0.f,0.f};

#define GQ_STAGE(KK) do { \
    __builtin_amdgcn_global_load_lds((glb_u32*)(pB1 + (KK)*32), (lds_u32*)&Bs[(KK)%3][(size_t)L1*8], 16, 0, 0); \
    __builtin_amdgcn_global_load_lds((glb_u32*)(pB2 + (KK)*32), (lds_u32*)&Bs[(KK)%3][(size_t)L2*8], 16, 0, 0); \
  } while(0)

#define GQ_STEP(KK, WS) do { \
    asm volatile("s_waitcnt vmcnt(" WS ") lgkmcnt(0)" ::: "memory"); \
    __builtin_amdgcn_s_barrier(); \
    __builtin_amdgcn_sched_barrier(0); \
    if ((KK) <= 13) GQ_STAGE((KK)+2); \
    const short8 ca0 = a0, ca1 = a1; \
    if ((KK) < 15){ \
      a0 = *(const short8*)(wbf + aofs0 + ((KK)+1)*32); \
      a1 = *(const short8*)(wbf + aofs1 + ((KK)+1)*32); \
    } \
    const int bi_ = (KK)%3; \
    _Pragma("unroll") \
    for (int nt = 0; nt < 7; ++nt){ \
      const short8 bfv = *(const short8*)&Bs[bi_][(q16*128 + nt*16 + l16)*8]; \
      acc[0][nt] = __builtin_amdgcn_mfma_f32_16x16x32_bf16(ca0, bfv, acc[0][nt], 0, 0, 0); \
      acc[1][nt] = __builtin_amdgcn_mfma_f32_16x16x32_bf16(ca1, bfv, acc[1][nt], 0, 0, 0); \
    } } while(0)

  GQ_STAGE(0); GQ_STAGE(1);
  short8 a0 = *(const short8*)(wbf + aofs0);
  short8 a1 = *(const short8*)(wbf + aofs1);
  GQ_STEP(0,"4");  GQ_STEP(1,"4");  GQ_STEP(2,"4");  GQ_STEP(3,"4");
  GQ_STEP(4,"4");  GQ_STEP(5,"4");  GQ_STEP(6,"4");  GQ_STEP(7,"4");
  GQ_STEP(8,"4");  GQ_STEP(9,"4");  GQ_STEP(10,"4"); GQ_STEP(11,"4");
  GQ_STEP(12,"4"); GQ_STEP(13,"4"); GQ_STEP(14,"4"); GQ_STEP(15,"2");

#undef GQ_STEP
#undef GQ_STAGE

  // C-write
  unsigned short* dst = (unsigned short*)qkv;
  #pragma unroll
  for (int nt = 0; nt < 7; ++nt){
    const int j  = nt*16 + l16;
    const int bs = (j >= 56);
    const int h  = j - 56*bs;
    #pragma unroll
    for (int mt = 0; mt < 2; ++mt){
      const int orow = o0 + wv*32 + mt*16 + q16*4;
      size_t base = ((size_t)(b0 + bs)*OO + orow)*HH + h;
      #pragma unroll
      for (int r = 0; r < 4; ++r)
        dst[base + (size_t)r*HH] = f2u(acc[mt][nt][r]);
    }
  }

  // fused BN1 partial stats (f32 accs, pre-rounding); all 112 j-cols are valid samples.
  // LDS scratch (Bs reuse) -> one 64-slot-spread atomic per thread (7 contenders/addr).
  __syncthreads();               // all MFMA LDS reads done before Bs reuse
  float* fb32 = (float*)Bs;      // 256 floats
  #pragma unroll
  for (int mt = 0; mt < 2; ++mt)
    #pragma unroll
    for (int r = 0; r < 4; ++r){
      float s = 0.f, q = 0.f;
      #pragma unroll
      for (int nt = 0; nt < 7; ++nt){ float v = acc[mt][nt][r]; s += v; q += v*v; }
      s += __shfl_xor(s, 1); q += __shfl_xor(q, 1);
      s += __shfl_xor(s, 2); q += __shfl_xor(q, 2);
      s += __shfl_xor(s, 4); q += __shfl_xor(q, 4);
      s += __shfl_xor(s, 8); q += __shfl_xor(q, 8);
      if (l16 == 0){
        const int rl = wv*32 + mt*16 + q16*4 + r;   // [0,128)
        fb32[rl*2]     = s;
        fb32[rl*2 + 1] = q;
      }
    }
  __syncthreads();
  atomicAdd(&pst1[(size_t)(fb & 63)*2048 + fo*256 + t], fb32[t]);
}

// ---------------- fold BN1 64-slot partials -> scale/shift ----------------
__global__ __launch_bounds__(256) void kFin1(const float* __restrict__ pst1,
                                             const void* __restrict__ gamma, const void* __restrict__ beta,
                                             float* __restrict__ sc, float* __restrict__ sh,
                                             const int* __restrict__ dflag){
  const bool f32 = (*dflag != 0);
  const int fo = blockIdx.x;     // 8 blocks
  const int t = threadIdx.x;
  float tot = 0.f;
  for (int s = 0; s < 64; ++s) tot += pst1[(size_t)s*2048 + fo*256 + t];
  __shared__ float sd[256];
  sd[t] = tot;                   // index t = rl*2 + stat
  __syncthreads();
  if (t < 128){
    float S = sd[t*2], Q = sd[t*2 + 1];
    const int ch = fo*128 + t;
    const float cnt = (float)(BB*HH);
    float mean = S / cnt;
    float var  = Q / cnt - mean*mean;
    float scale = ldin(gamma, ch, f32) * rsqrtf(var + EPSV);
    sc[ch] = scale; sh[ch] = ldin(beta, ch, f32) - mean*scale;
  }
}

// ============ shared helpers ============
static __device__ __forceinline__ void stageQK(unsigned short* sm, const unsigned short* qkv,
                                               const float* __restrict__ sc1, const float* __restrict__ sh1,
                                               int b, int g, int t){
  const unsigned short* qp = qkv + (size_t)(b*OO + g*128)*HH;
  for (int q = t; q < 896; q += 256){           // q/k rows, ushort4
    int c = q / 14, hq = q - c*14;
    int o = g*128 + c;
    ushort4 u = *(const ushort4*)(qp + (size_t)c*HH + hq*4);
    float s = sc1[o], hb = sh1[o];
    int base = (c < 32 ? A2_QT : A2_KT) + (c & 31) + hq*160;
    sm[base]       = f2u(u2f(u.x)*s + hb);
    sm[base + 40]  = f2u(u2f(u.y)*s + hb);
    sm[base + 80]  = f2u(u2f(u.z)*s + hb);
    sm[base + 120] = f2u(u2f(u.w)*s + hb);
  }
  for (int i = t; i < 640; i += 256){           // zero rows 56..63 of qT/kT
    int a = i / 320, r = i - a*320;
    sm[(a ? A2_KT : A2_QT) + 2240 + r] = 0;
  }
}

static __device__ __forceinline__ void scoreMFMA(const unsigned short* sm,
                                                 const unsigned short* __restrict__ relpad,
                                                 int w, int q16, int l16,
                                                 f32x4 aqk[4], f32x4 aU[7], f32x4 aV[7]){
  const short8 aq = *(const short8*)&sm[A2_QT + (w*16 + l16)*40 + q16*8];
  const short8 ak = *(const short8*)&sm[A2_KT + (w*16 + l16)*40 + q16*8];
  #pragma unroll
  for (int nt = 0; nt < 4; ++nt){
    const short8 bk = *(const short8*)&sm[A2_KT + (nt*16 + l16)*40 + q16*8];
    aqk[nt] = __builtin_amdgcn_mfma_f32_16x16x32_bf16(aq, bk, aqk[nt], 0, 0, 0);
  }
  #pragma unroll
  for (int nt = 0; nt < 7; ++nt){
    const short8 bq = *(const short8*)(relpad + RP_RQ + (nt*16 + l16)*40 + q16*8);
    const short8 br = *(const short8*)(relpad + RP_RK + (nt*16 + l16)*40 + q16*8);
    aU[nt] = __builtin_amdgcn_mfma_f32_16x16x32_bf16(aq, bq, aU[nt], 0, 0, 0);
    aV[nt] = __builtin_amdgcn_mfma_f32_16x16x32_bf16(ak, br, aV[nt], 0, 0, 0);
  }
}

static __device__ __forceinline__ void writeUV(unsigned short* sm, int w, int q16, int l16,
                                               const f32x4 aU[7], const f32x4 aV[7]){
  #pragma unroll
  for (int nt = 0; nt < 7; ++nt){
    const int d = nt*16 + l16;
    #pragma unroll
    for (int r = 0; r < 4; ++r){
      const int i = w*16 + q16*4 + r;
      if (i < HH){
        sm[A2_UL + i*116 + d] = f2u(aU[nt][r]);   // stride 116: q16 groups on
        sm[A2_VL + i*116 + d] = f2u(aV[nt][r]);   // disjoint bank spans
      }
    }
  }
}

// ---------------- kScore: MFMA scores -> BN2 stats, all in registers ----------------
__global__ __launch_bounds__(256) void kScore(const bf16* __restrict__ qkv,
                                              const unsigned short* __restrict__ relpad,
                                              const float* __restrict__ sc1, const float* __restrict__ sh1,
                                              float* __restrict__ psum, float* __restrict__ psq){
  const int b = blockIdx.x, g = blockIdx.y;
  __shared__ __align__(16) unsigned short sm[5120];   // qT/kT only (10 KB)
  __shared__ float red[6][4];
  const int t = threadIdx.x;
  const int lane = t & 63, w = t >> 6;
  const int q16 = lane >> 4, l16 = lane & 15;

  stageQK(sm, (const unsigned short*)qkv, sc1, sh1, b, g, t);
  __syncthreads();

  f32x4 aqk[4], aU[7], aV[7];
  #pragma unroll
  for (int nt = 0; nt < 4; ++nt) aqk[nt] = (f32x4){0.f,0.f,0.f,0.f};
  #pragma unroll
  for (int nt = 0; nt < 7; ++nt){ aU[nt] = (f32x4){0.f,0.f,0.f,0.f}; aV[nt] = (f32x4){0.f,0.f,0.f,0.f}; }
  scoreMFMA(sm, relpad, w, q16, l16, aqk, aU, aV);

  float s0=0.f,s1=0.f,s2=0.f,p0=0.f,p1=0.f,p2=0.f;
  #pragma unroll
  for (int nt = 0; nt < 4; ++nt){
    const int j = nt*16 + l16;
    #pragma unroll
    for (int r = 0; r < 4; ++r){
      const int i = w*16 + q16*4 + r;
      if (i < HH && j < HH){ float v = aqk[nt][r]; s0 += v; p0 += v*v; }
    }
  }
  #pragma unroll
  for (int nt = 0; nt < 7; ++nt){
    const int d = nt*16 + l16;
    #pragma unroll
    for (int r = 0; r < 4; ++r){
      const int row = w*16 + q16*4 + r;
      if (row < HH && (unsigned)(d - row) < (unsigned)HH){
        float u = aU[nt][r]; s1 += u; p1 += u*u;
        float v = aV[nt][r]; s2 += v; p2 += v*v;
      }
    }
  }
  float s[3] = {s0,s1,s2}, q2[3] = {p0,p1,p2};
  #pragma unroll
  for (int off = 32; off > 0; off >>= 1)
    #pragma unroll
    for (int m = 0; m < 3; ++m){ s[m]+=__shfl_down(s[m],off); q2[m]+=__shfl_down(q2[m],off); }
  if ((t & 63) == 0){
    #pragma unroll
    for (int m = 0; m < 3; ++m){ red[m][w] = s[m]; red[3+m][w] = q2[m]; }
  }
  __syncthreads();
  if (t < 6){
    float v = red[t][0]+red[t][1]+red[t][2]+red[t][3];
    int m = t % 3;
    int ch = m*8 + g;
    float* dstp = (t >= 3) ? psq : psum;
    atomicAdd(&dstp[(b & 7)*24 + ch], v);    // 8-slot spread
  }
}

__global__ void kF2(const float* __restrict__ psum, const float* __restrict__ psq,
                    const void* __restrict__ gs, const void* __restrict__ bs,
                    float* __restrict__ sc2, float* __restrict__ sh2,
                    const int* __restrict__ dflag){
  const bool f32 = (*dflag != 0);
  const int ch = threadIdx.x;
  if (ch < 24){
    float S = 0.f, Q = 0.f;
    for (int sl = 0; sl < 8; ++sl){ S += psum[sl*24 + ch]; Q += psq[sl*24 + ch]; }
    const float cnt = (float)BB * (float)(HH*HH);
    float mean = S / cnt;
    float var  = Q / cnt - mean*mean;
    float scale = ldin(gs, ch, f32) * rsqrtf(var + EPSV);
    sc2[ch] = scale; sh2[ch] = ldin(bs, ch, f32) - mean*scale;
  }
}

// ---------------- kAttn2: scores -> BN2 -> softmax -> PV (BN3 partials -> pst3) ----------------
__global__ __launch_bounds__(256) void kAttn2(const bf16* __restrict__ qkv,
                                              const unsigned short* __restrict__ relpad,
                                              const float* __restrict__ sc1, const float* __restrict__ sh1,
                                              const float* __restrict__ sc2, const float* __restrict__ sh2,
                                              bf16* __restrict__ outr,
                                              float* __restrict__ pst3){
  const int b = blockIdx.x, g = blockIdx.y;
  __shared__ __align__(16) unsigned short sm[A2_TOT];
  const int t = threadIdx.x;
  const int lane = t & 63, w = t >> 6;
  const int q16 = lane >> 4, l16 = lane & 15;

  // phase 1: q/k staging only (rel stays in global/L1)
  stageQK(sm, (const unsigned short*)qkv, sc1, sh1, b, g, t);
  __syncthreads();

  // phase 2: score MFMAs
  f32x4 aqk[4], aU[7], aV[7];
  #pragma unroll
  for (int nt = 0; nt < 4; ++nt) aqk[nt] = (f32x4){0.f,0.f,0.f,0.f};
  #pragma unroll
  for (int nt = 0; nt < 7; ++nt){ aU[nt] = (f32x4){0.f,0.f,0.f,0.f}; aV[nt] = (f32x4){0.f,0.f,0.f,0.f}; }
  scoreMFMA(sm, relpad, w, q16, l16, aqk, aU, aV);
  __syncthreads();

  // phase 3: Ul/Vl overlay (stride 116)
  writeUV(sm, w, q16, l16, aU, aV);
  __syncthreads();

  // phase 4: sim = BN2(qk)+BN2(qr)+BN2(kr), f16
  {
    const float scqk=sc2[g],    shqk=sh2[g];
    const float scqr=sc2[8+g],  shqr=sh2[8+g];
    const float sckr=sc2[16+g], shkr=sh2[16+g];
    _Float16* simh = (_Float16*)&sm[A2_SIM];
    #pragma unroll
    for (int nt = 0; nt < 4; ++nt){
      const int j = nt*16 + l16;
      #pragma unroll
      for (int r = 0; r < 4; ++r){
        const int i = w*16 + q16*4 + r;
        if (i < HH && j < HH){
          float qr = u2f(sm[A2_UL + i*116 + (i - j + 55)]);
          float kr = u2f(sm[A2_VL + j*116 + (j - i + 55)]);
          float sv_ = aqk[nt][r]*scqk + shqk + qr*scqr + shqr + kr*sckr + shkr;
          simh[i*60 + j] = (_Float16)sv_;
        }
      }
    }
  }
  __syncthreads();

  // phase 5: zero P/S' (13312u = 6656 dwords)
  for (int i = t; i < 6656; i += 256) ((unsigned int*)sm)[i] = 0u;
  __syncthreads();

  // phase 6: softmax rows -> P and gathered S'
  if (t < 224){
    const _Float16* simh = (const _Float16*)&sm[A2_SIM];
    const int r = t >> 2, l4 = t & 3;
    float pvv[14]; float mx = -1e30f;
    #pragma unroll
    for (int m = 0; m < 14; ++m){ pvv[m] = (float)simh[r*60 + l4 + 4*m]; mx = fmaxf(mx, pvv[m]); }
    mx = fmaxf(mx, __shfl_xor(mx, 1)); mx = fmaxf(mx, __shfl_xor(mx, 2));
    float smm = 0.f;
    #pragma unroll
    for (int m = 0; m < 14; ++m){ pvv[m] = __expf(pvv[m] - mx); smm += pvv[m]; }
    smm += __shfl_xor(smm, 1); smm += __shfl_xor(smm, 2);
    const float inv = 1.f / smm;
    #pragma unroll
    for (int m = 0; m < 14; ++m){
      const int j = l4 + 4*m;
      unsigned short pu = f2u(pvv[m]*inv);
      sm[A2_P  + r*72  + j]            = pu;
      sm[A2_SP + r*136 + (r - j + 55)] = pu;
    }
  }
  __syncthreads();

  // phase 7: PV in two c-halves (v staged into dead sim region; Rv read direct)
  f32x4 asv[4], asve[4];
  #pragma unroll
  for (int nt = 0; nt < 4; ++nt){ asv[nt] = (f32x4){0.f,0.f,0.f,0.f}; asve[nt] = (f32x4){0.f,0.f,0.f,0.f}; }
  const short8 ap0 = *(const short8*)&sm[A2_P + (w*16 + l16)*72 + q16*8];
  const short8 ap1 = *(const short8*)&sm[A2_P + (w*16 + l16)*72 + 32 + q16*8];
  short8 asp[4];
  #pragma unroll
  for (int kk = 0; kk < 4; ++kk)
    asp[kk] = *(const short8*)&sm[A2_SP + (w*16 + l16)*136 + kk*32 + q16*8];

  #pragma unroll
  for (int half = 0; half < 2; ++half){
    const unsigned short* vp = (const unsigned short*)qkv
        + ((size_t)b*OO + g*128 + 64 + half*32)*HH;
    for (int q = t; q < 448; q += 256){
      int c2 = q / 14, hq = q - c2*14;
      int o = g*128 + 64 + half*32 + c2;
      ushort4 u = *(const ushort4*)(vp + (size_t)c2*HH + hq*4);
      float s = sc1[o], hb = sh1[o];
      unsigned short* d = &sm[A2_VH + c2*72 + hq*4];
      d[0] = f2u(u2f(u.x)*s + hb);
      d[1] = f2u(u2f(u.y)*s + hb);
      d[2] = f2u(u2f(u.z)*s + hb);
      d[3] = f2u(u2f(u.w)*s + hb);
    }
    { int c2 = t >> 3, e = t & 7; sm[A2_VH + c2*72 + 56 + e] = 0; }
    __syncthreads();
    #pragma unroll
    for (int ntl = 0; ntl < 2; ++ntl){
      const int nt = half*2 + ntl;
      const short8 bv0 = *(const short8*)&sm[A2_VH + (ntl*16 + l16)*72 + q16*8];
      const short8 bv1 = *(const short8*)&sm[A2_VH + (ntl*16 + l16)*72 + 32 + q16*8];
      asv[nt] = __builtin_amdgcn_mfma_f32_16x16x32_bf16(ap0, bv0, asv[nt], 0, 0, 0);
      asv[nt] = __builtin_amdgcn_mfma_f32_16x16x32_bf16(ap1, bv1, asv[nt], 0, 0, 0);
      #pragma unroll
      for (int kk = 0; kk < 4; ++kk){
        const short8 br = *(const short8*)(relpad + RP_RV
            + (size_t)(half*32 + ntl*16 + l16)*136 + kk*32 + q16*8);
        asve[nt] = __builtin_amdgcn_mfma_f32_16x16x32_bf16(asp[kk], br, asve[nt], 0, 0, 0);
      }
    }
    __syncthreads();
  }

  // epilogue: C-write
  const int i0 = w*16 + q16*4;
  if (i0 < HH){
    unsigned short* op = (unsigned short*)outr + (size_t)b*OO*HH;
    #pragma unroll
    for (int nt = 0; nt < 4; ++nt){
      const int c = nt*16 + l16;
      const int och = (g*64 + c)*2;
      *(ushort4*)(op + (size_t)och*HH + i0) =
        make_ushort4(f2u(asv[nt][0]),  f2u(asv[nt][1]),  f2u(asv[nt][2]),  f2u(asv[nt][3]));
      *(ushort4*)(op + (size_t)(och+1)*HH + i0) =
        make_ushort4(f2u(asve[nt][0]), f2u(asve[nt][1]), f2u(asve[nt][2]), f2u(asve[nt][3]));
    }
  }

  // fused BN3 partial stats -> 64-slot-spread (14 contenders/addr)
  {
    float* fr = (float*)sm;
    const bool ivalid = (i0 < HH);
    #pragma unroll
    for (int nt = 0; nt < 4; ++nt){
      float ssv = 0.f, qsv = 0.f, ssve = 0.f, qsve = 0.f;
      if (ivalid){
        #pragma unroll
        for (int r = 0; r < 4; ++r){
          float a = asv[nt][r], e2 = asve[nt][r];
          ssv += a; qsv += a*a; ssve += e2; qsve += e2*e2;
        }
      }
      ssv  += __shfl_xor(ssv, 16);  ssv  += __shfl_xor(ssv, 32);
      qsv  += __shfl_xor(qsv, 16);  qsv  += __shfl_xor(qsv, 32);
      ssve += __shfl_xor(ssve, 16); ssve += __shfl_xor(ssve, 32);
      qsve += __shfl_xor(qsve, 16); qsve += __shfl_xor(qsve, 32);
      if (q16 == 0)
        *(f32x4*)&fr[(size_t)w*256 + (nt*16 + l16)*4] = (f32x4){ssv, qsv, ssve, qsve};
    }
    __syncthreads();
    float xv = fr[t] + fr[256 + t] + fr[512 + t] + fr[768 + t];
    atomicAdd(&pst3[(size_t)(b & 63)*2048 + g*256 + t], xv);
  }
}

// ---------------- fold BN3 64-slot partials -> scale/shift ----------------
__global__ __launch_bounds__(256) void kFin3(const float* __restrict__ pst3,
                                             const void* __restrict__ gamma, const void* __restrict__ beta,
                                             float* __restrict__ sc, float* __restrict__ sh,
                                             const int* __restrict__ dflag){
  const bool f32 = (*dflag != 0);
  const int g = blockIdx.x;      // 8 blocks
  const int t = threadIdx.x;
  float tot = 0.f;
  for (int s = 0; s < 64; ++s) tot += pst3[(size_t)s*2048 + g*256 + t];
  // t encodes: v=t&3, nt=t>>6, l16v=(t>>2)&15 -> och_local=(nt*16+l16v)*2+(v>>1), stat=v&1
  __shared__ float sd[256];
  const int v = t & 3, nt = t >> 6, l16v = (t >> 2) & 15;
  const int ol = (nt*16 + l16v)*2 + (v >> 1);
  sd[ol*2 + (v & 1)] = tot;
  __syncthreads();
  if (t < 128){
    float S = sd[t*2], Q = sd[t*2 + 1];
    const int ch = g*128 + t;
    const float cnt = (float)(BB*HH);
    float mean = S / cnt;
    float var  = Q / cnt - mean*mean;
    float scale = ldin(gamma, ch, f32) * rsqrtf(var + EPSV);
    sc[ch] = scale; sh[ch] = ldin(beta, ch, f32) - mean*scale;
  }
}

// ---------------- BN3 + pair-sum + transpose to (N,512,H,W) ----------------
__global__ __launch_bounds__(256) void kOut(const bf16* __restrict__ outr, const float* __restrict__ sc3,
                                            const float* __restrict__ sh3, void* __restrict__ out,
                                            const int* __restrict__ dflag){
  const bool f32 = (*dflag != 0);
  const int p = blockIdx.x, n = blockIdx.y;
  __shared__ float tile[HH][WW+2];
  const unsigned short* ip = (const unsigned short*)outr;
  const float s0 = sc3[2*p], h0 = sh3[2*p], s1 = sc3[2*p+1], h1 = sh3[2*p+1];
  for (int idx = threadIdx.x; idx < 392; idx += 256){     // 56 w x 7 h-octs
    int w = idx / 7, h8 = idx - w*7;
    size_t base = ((size_t)((n*WW + w)*OO) + 2*p)*HH + h8*8;
    short8 ua = *(const short8*)(ip + base);
    short8 ub = *(const short8*)(ip + base + HH);
    #pragma unroll
    for (int e = 0; e < 8; ++e)
      tile[h8*8+e][w] = u2f((unsigned short)ua[e])*s0 + h0 + u2f((unsigned short)ub[e])*s1 + h1;
  }
  __syncthreads();
  const size_t obase = ((size_t)(n*512 + p))*HH*WW;
  for (int idx = threadIdx.x; idx < 784; idx += 256){     // 56 h x 14 w-quads
    int h = idx / 14, w4 = idx - h*14;
    float4 v = make_float4(tile[h][w4*4], tile[h][w4*4+1], tile[h][w4*4+2], tile[h][w4*4+3]);
    if (f32){
      *(float4*)((float*)out + obase + (size_t)h*WW + w4*4) = v;
    } else {
      *(ushort4*)((unsigned short*)out + obase + (size_t)h*WW + w4*4) =
        make_ushort4(f2u(v.x), f2u(v.y), f2u(v.z), f2u(v.w));
    }
  }
}

extern "C" void kernel_launch(void* const* d_in, const int* in_sizes, int n_in,
                              void* d_out, int out_size, void* d_ws, size_t ws_size,
                              hipStream_t stream){
  (void)in_sizes; (void)n_in; (void)out_size; (void)ws_size;
  const void* x    = d_in[0];
  const void* wqkv = d_in[1];
  const void* rel  = d_in[2];
  const void* gq   = d_in[3];
  const void* bq   = d_in[4];
  const void* gs   = d_in[5];
  const void* bs   = d_in[6];
  const void* go   = d_in[7];
  const void* bo   = d_in[8];

  char* ws = (char*)d_ws;
  const size_t szA = (size_t)BB*OO*HH*2;   // 102,760,448 B
  bf16* xtk  = (bf16*)ws;                  // [B][H][C]  (dead after GEMM)
  bf16* outr = (bf16*)ws;                  // [B][O][H]  (reuses region A)
  unsigned short* wbf = (unsigned short*)(ws + (size_t)64*1024*1024);   // 1 MB
  bf16* qkv  = (bf16*)(ws + szA);          // [B][O][H]
  float* st  = (float*)(ws + 2*szA);
  float* sc1   = st;
  float* sh1   = st + 1024;
  float* sc3   = st + 2048;
  float* sh3   = st + 3072;
  float* sc2   = st + 4096;
  float* sh2   = st + 4128;
  int*   flag  = (int*)(st + 4160);
  // kDetect zeroes st[2048 .. 7424):
  float* psum   = st + 4352;               // BN2 [8][24]
  float* psq    = st + 4544;               // BN2 [8][24]
  unsigned short* relpad = (unsigned short*)(ws + 2*szA + 32768);  // 17664u, ends +68096
  float* pstG = (float*)(ws + 2*szA + 69632);   // 1 MB: pst1 [64][2048] + pst3 [64][2048]
  float* pst1 = pstG;
  float* pst3 = pstG + 131072;

  kDetect <<<1, 128, 0, stream>>>(x, st + 2048, flag);
  kPrep   <<<1, 256, 0, stream>>>(rel, relpad, flag);
  kWPrep  <<<2048, 256, 0, stream>>>(wqkv, wbf, pstG, flag);
  kTrans  <<<dim3(HH, 4, NN), 256, 0, stream>>>(x, xtk, flag);
  kGemmQKV<<<dim3(8, BB/2), 256, 0, stream>>>(wbf, xtk, qkv, pst1);
  kFin1   <<<8, 256, 0, stream>>>(pst1, gq, bq, sc1, sh1, flag);
  kScore  <<<dim3(BB, GG), 256, 0, stream>>>(qkv, relpad, sc1, sh1, psum, psq);
  kF2     <<<1, 64, 0, stream>>>(psum, psq, gs, bs, sc2, sh2, flag);
  kAttn2  <<<dim3(BB, GG), 256, 0, stream>>>(qkv, relpad, sc1, sh1, sc2, sh2, outr, pst3);
  kFin3   <<<8, 256, 0, stream>>>(pst3, go, bo, sc3, sh3, flag);
  kOut    <<<dim3(512, NN), 256, 0, stream>>>(outr, sc3, sh3, d_out, flag);
}

// Round 10
// 568.748 us; speedup vs baseline: 1.2320x; 1.0057x over previous
//
#include <hip/hip_runtime.h>
#include <hip/hip_bf16.h>

typedef __hip_bfloat16 bf16;
typedef __attribute__((ext_vector_type(8))) short short8;
typedef __attribute__((ext_vector_type(4))) float f32x4;

#define NN   16
#define CIN  512
#define HH   56
#define WW   56
#define BB   (NN*WW)     /* 896 */
#define OO   1024
#define GG   8
#define RL   111         /* 2K-1 */
#define EPSV 1e-5f

// ---- shared LDS layout for kAttn2 (ushort offsets) ----
#define A2_QT  0         /* qT  [64 rows h][40u] cols c0..31          */
#define A2_KT  2560      /* kT  [64][40u]   (inputs end 5120)         */
#define A2_UL  0         /* Ul [56 i][116u d] (stride 116: bank-clean)*/
#define A2_VL  6496      /* Vl [56][116u]     (end 12992)             */
#define A2_P   0         /* P  [64 i][72u j]   overlay after phase 4  */
#define A2_SP  4608      /* S' [64 i][128u d]  (end 12800)            */
#define A2_SIM 12992     /* sim f16 [56][60]   (end 16352; must be    */
                         /* >= VL end: phase 4 reads VL, writes SIM)  */
#define A2_VH  12992     /* v half [32 c][72u j] phase 7 (SIM dead)   */
#define A2_TOT 16352     /* 32704 B -> 5 blocks/CU                    */

// relpad (ws) ushort offsets
#define RP_RQ 0          /* [112][40]  4480u */
#define RP_RK 4480       /* [112][40]  4480u */
#define RP_RV 8960       /* [64][136]  8704u  (end 17664) */

static __device__ __forceinline__ float u2f(unsigned short u){
  union { unsigned int i; float f; } x; x.i = ((unsigned int)u) << 16; return x.f;
}
static __device__ __forceinline__ unsigned short f2u(float f){
  union { float f; unsigned int i; } x; x.f = f;
  unsigned int i = x.i;
  unsigned int r = i + 0x7FFFu + ((i >> 16) & 1u);   // RNE
  return (unsigned short)(r >> 16);
}
static __device__ __forceinline__ float ldin(const void* p, size_t i, bool f32){
  return f32 ? ((const float*)p)[i] : u2f(((const unsigned short*)p)[i]);
}

typedef __attribute__((address_space(3))) unsigned int lds_u32;
typedef __attribute__((address_space(1))) const unsigned int glb_u32;

// ---------------- dtype probe + BN2 partial-stat zeroing ----------------
__global__ void kDetect(const void* __restrict__ x, float* __restrict__ part, int* __restrict__ flag){
  const int t = threadIdx.x;     // 128 threads
  for (int i = t; i < 5376; i += 128) part[i] = 0.f;   // st[2048..7424)
  unsigned short u = ((const unsigned short*)x)[t];
  int e = (u >> 7) & 0xFF;
  int bad = (e < 100 || e > 140) ? 1 : 0;
  __shared__ int cnt;
  if (t == 0) cnt = 0;
  __syncthreads();
  if (bad) atomicAdd(&cnt, 1);
  __syncthreads();
  if (t == 0) *flag = (cnt > 16) ? 1 : 0;   // 1 => inputs are fp32
}

// ---------------- build padded/transposed rel images in ws (once) ----------------
__global__ __launch_bounds__(256) void kPrep(const void* __restrict__ rel, unsigned short* __restrict__ relpad,
                                             const int* __restrict__ dflag){
  const bool f32 = (*dflag != 0);
  const int t = threadIdx.x;
  for (int i = t; i < 8960; i += 256){          // RqT / RkT  [d][c]
    int reg = i / 4480, r = i - reg*4480;
    int d = r / 40, c = r - d*40;
    float v = (d < RL && c < 32) ? ldin(rel, (size_t)(reg*32 + c)*RL + d, f32) : 0.f;
    relpad[i] = f2u(v);
  }
  for (int i = t; i < 8704; i += 256){          // Rv [c][d]
    int c = i / 136, d = i - c*136;
    float v = (d < RL) ? ldin(rel, (size_t)(64 + c)*RL + d, f32) : 0.f;
    relpad[RP_RV + i] = f2u(v);
  }
}

// ---------------- pre-convert w_qkv to bf16 + zero pstG (once) ----------------
__global__ __launch_bounds__(256) void kWPrep(const void* __restrict__ w, unsigned short* __restrict__ wbf,
                                              float* __restrict__ pstG, const int* __restrict__ dflag){
  const bool f32 = (*dflag != 0);
  const size_t i = (size_t)blockIdx.x*256 + threadIdx.x;   // 2048*256 = 524288 = 1024*512
  wbf[i] = f2u(ldin(w, i, f32));
  if (blockIdx.x < 256){   // zero 256*256*4 = 262144 floats = pst1 + pst3 (1 MB)
    ((f32x4*)pstG)[(size_t)blockIdx.x*256 + threadIdx.x] = (f32x4){0.f,0.f,0.f,0.f};
  }
}

// ---------------- transpose x (N,C,H,W) -> xtk[b=(n*W+w)][h][c] ----------------
__global__ __launch_bounds__(256) void kTrans(const void* __restrict__ x, bf16* __restrict__ xtk,
                                              const int* __restrict__ dflag){
  const bool f32 = (*dflag != 0);
  const int h  = blockIdx.x;       // 56
  const int cg = blockIdx.y;       // 4 groups of 128 channels
  const int n  = blockIdx.z;       // 16
  __shared__ unsigned short tile[128][58];
  const size_t rbase = (((size_t)n*CIN + cg*128)*HH + h)*WW;
  if (f32){
    const float* xp = (const float*)x;
    for (int idx = threadIdx.x; idx < 128*14; idx += 256){
      int ci = idx / 14, w4 = idx - ci*14;
      float4 v = *(const float4*)(xp + rbase + (size_t)ci*HH*WW + w4*4);
      tile[ci][w4*4]   = f2u(v.x);
      tile[ci][w4*4+1] = f2u(v.y);
      tile[ci][w4*4+2] = f2u(v.z);
      tile[ci][w4*4+3] = f2u(v.w);
    }
  } else {
    for (int idx = threadIdx.x; idx < 128*WW; idx += 256){
      int ci = idx / WW, w = idx - ci*WW;
      tile[ci][w] = f2u(ldin(x, rbase + (size_t)ci*HH*WW + w, f32));
    }
  }
  __syncthreads();
  unsigned short* dst = (unsigned short*)xtk;
  for (int idx = threadIdx.x; idx < WW*16; idx += 256){
    int w = idx >> 4, c8 = idx & 15;
    short8 o;
    #pragma unroll
    for (int e = 0; e < 8; ++e) o[e] = (short)tile[c8*8+e][w];
    *(short8*)(dst + ((size_t)(n*WW + w)*HH + h)*CIN + cg*128 + c8*8) = o;
  }
}

// ---------------- MFMA GEMM: qkv[b][o][h] = sum_c w[o][c] * xtk[b][h][c] ----------------
// B: 3-deep counted-vmcnt global_load_lds; A: register prefetch from L2-hot wbf.
__global__ __launch_bounds__(256) void kGemmQKV(const unsigned short* __restrict__ wbf,
                                                const bf16* __restrict__ xtk,
                                                bf16* __restrict__ qkv,
                                                float* __restrict__ pst1){
  // bijective XCD swizzle: each XCD gets 56 consecutive b-pairs x all 8 o-blocks
  const int id = blockIdx.x + (blockIdx.y << 3);      // grid (8,448)
  const int lb = (id & 7)*448 + (id >> 3);
  const int fo = lb & 7, fb = lb >> 3;
  const int o0 = fo * 128;
  const int b0 = fb * 2;
  const int t  = threadIdx.x;
  const int lane = t & 63, wv = t >> 6;
  const int q16 = lane >> 4, l16 = lane & 15;

  __shared__ __align__(16) unsigned short Bs[3][4096];   // [k8][128 cols][8]

  const int L1 = t, L2 = t + 256;
  const int k81 = L1 >> 7, j1 = L1 & 127;
  const int k82 = L2 >> 7, j2 = L2 & 127;
  const int je1 = (j1 < 112) ? j1 : 111;   // pad cols 112..127 (never consumed)
  const int je2 = (j2 < 112) ? j2 : 111;
  const int bs1 = (je1 >= 56), bs2 = (je2 >= 56);
  const unsigned short* pB1 = (const unsigned short*)xtk
      + ((size_t)(b0 + bs1)*HH + (je1 - 56*bs1))*CIN + k81*8;
  const unsigned short* pB2 = (const unsigned short*)xtk
      + ((size_t)(b0 + bs2)*HH + (je2 - 56*bs2))*CIN + k82*8;
  const size_t aofs0 = (size_t)(o0 + wv*32 + l16)*CIN + q16*8;
  const size_t aofs1 = aofs0 + (size_t)16*CIN;

  f32x4 acc[2][7];
  #pragma unroll
  for (int mt = 0; mt < 2; ++mt)
    #pragma unroll
    for (int nt = 0; nt < 7; ++nt) acc[mt][nt] = (f32x4){0.f,0.f,0.f,0.f};

#define GQ_STAGE(KK) do { \
    __builtin_amdgcn_global_load_lds((glb_u32*)(pB1 + (KK)*32), (lds_u32*)&Bs[(KK)%3][(size_t)L1*8], 16, 0, 0); \
    __builtin_amdgcn_global_load_lds((glb_u32*)(pB2 + (KK)*32), (lds_u32*)&Bs[(KK)%3][(size_t)L2*8], 16, 0, 0); \
  } while(0)

#define GQ_STEP(KK, WS) do { \
    asm volatile("s_waitcnt vmcnt(" WS ") lgkmcnt(0)" ::: "memory"); \
    __builtin_amdgcn_s_barrier(); \
    __builtin_amdgcn_sched_barrier(0); \
    if ((KK) <= 13) GQ_STAGE((KK)+2); \
    const short8 ca0 = a0, ca1 = a1; \
    if ((KK) < 15){ \
      a0 = *(const short8*)(wbf + aofs0 + ((KK)+1)*32); \
      a1 = *(const short8*)(wbf + aofs1 + ((KK)+1)*32); \
    } \
    const int bi_ = (KK)%3; \
    _Pragma("unroll") \
    for (int nt = 0; nt < 7; ++nt){ \
      const short8 bfv = *(const short8*)&Bs[bi_][(q16*128 + nt*16 + l16)*8]; \
      acc[0][nt] = __builtin_amdgcn_mfma_f32_16x16x32_bf16(ca0, bfv, acc[0][nt], 0, 0, 0); \
      acc[1][nt] = __builtin_amdgcn_mfma_f32_16x16x32_bf16(ca1, bfv, acc[1][nt], 0, 0, 0); \
    } } while(0)

  GQ_STAGE(0); GQ_STAGE(1);
  short8 a0 = *(const short8*)(wbf + aofs0);
  short8 a1 = *(const short8*)(wbf + aofs1);
  GQ_STEP(0,"4");  GQ_STEP(1,"4");  GQ_STEP(2,"4");  GQ_STEP(3,"4");
  GQ_STEP(4,"4");  GQ_STEP(5,"4");  GQ_STEP(6,"4");  GQ_STEP(7,"4");
  GQ_STEP(8,"4");  GQ_STEP(9,"4");  GQ_STEP(10,"4"); GQ_STEP(11,"4");
  GQ_STEP(12,"4"); GQ_STEP(13,"4"); GQ_STEP(14,"4"); GQ_STEP(15,"2");

#undef GQ_STEP
#undef GQ_STAGE

  // C-write
  unsigned short* dst = (unsigned short*)qkv;
  #pragma unroll
  for (int nt = 0; nt < 7; ++nt){
    const int j  = nt*16 + l16;
    const int bs = (j >= 56);
    const int h  = j - 56*bs;
    #pragma unroll
    for (int mt = 0; mt < 2; ++mt){
      const int orow = o0 + wv*32 + mt*16 + q16*4;
      size_t base = ((size_t)(b0 + bs)*OO + orow)*HH + h;
      #pragma unroll
      for (int r = 0; r < 4; ++r)
        dst[base + (size_t)r*HH] = f2u(acc[mt][nt][r]);
    }
  }

  // fused BN1 partial stats; LDS scratch (Bs reuse) -> 64-slot-spread atomics
  __syncthreads();               // all MFMA LDS reads done before Bs reuse
  float* fb32 = (float*)Bs;      // 256 floats
  #pragma unroll
  for (int mt = 0; mt < 2; ++mt)
    #pragma unroll
    for (int r = 0; r < 4; ++r){
      float s = 0.f, q = 0.f;
      #pragma unroll
      for (int nt = 0; nt < 7; ++nt){ float v = acc[mt][nt][r]; s += v; q += v*v; }
      s += __shfl_xor(s, 1); q += __shfl_xor(q, 1);
      s += __shfl_xor(s, 2); q += __shfl_xor(q, 2);
      s += __shfl_xor(s, 4); q += __shfl_xor(q, 4);
      s += __shfl_xor(s, 8); q += __shfl_xor(q, 8);
      if (l16 == 0){
        const int rl = wv*32 + mt*16 + q16*4 + r;   // [0,128)
        fb32[rl*2]     = s;
        fb32[rl*2 + 1] = q;
      }
    }
  __syncthreads();
  atomicAdd(&pst1[(size_t)(fb & 63)*2048 + fo*256 + t], fb32[t]);
}

// ---------------- fold BN1 64-slot partials -> scale/shift ----------------
__global__ __launch_bounds__(256) void kFin1(const float* __restrict__ pst1,
                                             const void* __restrict__ gamma, const void* __restrict__ beta,
                                             float* __restrict__ sc, float* __restrict__ sh,
                                             const int* __restrict__ dflag){
  const bool f32 = (*dflag != 0);
  const int fo = blockIdx.x;     // 8 blocks
  const int t = threadIdx.x;
  float tot = 0.f;
  for (int s = 0; s < 64; ++s) tot += pst1[(size_t)s*2048 + fo*256 + t];
  __shared__ float sd[256];
  sd[t] = tot;                   // index t = rl*2 + stat
  __syncthreads();
  if (t < 128){
    float S = sd[t*2], Q = sd[t*2 + 1];
    const int ch = fo*128 + t;
    const float cnt = (float)(BB*HH);
    float mean = S / cnt;
    float var  = Q / cnt - mean*mean;
    float scale = ldin(gamma, ch, f32) * rsqrtf(var + EPSV);
    sc[ch] = scale; sh[ch] = ldin(beta, ch, f32) - mean*scale;
  }
}

// ============ shared helpers ============
static __device__ __forceinline__ void stageQK(unsigned short* sm, const unsigned short* qkv,
                                               const float* __restrict__ sc1, const float* __restrict__ sh1,
                                               int b, int g, int t){
  const unsigned short* qp = qkv + (size_t)(b*OO + g*128)*HH;
  for (int q = t; q < 896; q += 256){           // q/k rows, ushort4
    int c = q / 14, hq = q - c*14;
    int o = g*128 + c;
    ushort4 u = *(const ushort4*)(qp + (size_t)c*HH + hq*4);
    float s = sc1[o], hb = sh1[o];
    int base = (c < 32 ? A2_QT : A2_KT) + (c & 31) + hq*160;
    sm[base]       = f2u(u2f(u.x)*s + hb);
    sm[base + 40]  = f2u(u2f(u.y)*s + hb);
    sm[base + 80]  = f2u(u2f(u.z)*s + hb);
    sm[base + 120] = f2u(u2f(u.w)*s + hb);
  }
  for (int i = t; i < 640; i += 256){           // zero rows 56..63 of qT/kT
    int a = i / 320, r = i - a*320;
    sm[(a ? A2_KT : A2_QT) + 2240 + r] = 0;
  }
}

static __device__ __forceinline__ void scoreMFMA(const unsigned short* sm,
                                                 const unsigned short* __restrict__ relpad,
                                                 int w, int q16, int l16,
                                                 f32x4 aqk[4], f32x4 aU[7], f32x4 aV[7]){
  const short8 aq = *(const short8*)&sm[A2_QT + (w*16 + l16)*40 + q16*8];
  const short8 ak = *(const short8*)&sm[A2_KT + (w*16 + l16)*40 + q16*8];
  #pragma unroll
  for (int nt = 0; nt < 4; ++nt){
    const short8 bk = *(const short8*)&sm[A2_KT + (nt*16 + l16)*40 + q16*8];
    aqk[nt] = __builtin_amdgcn_mfma_f32_16x16x32_bf16(aq, bk, aqk[nt], 0, 0, 0);
  }
  #pragma unroll
  for (int nt = 0; nt < 7; ++nt){
    const short8 bq = *(const short8*)(relpad + RP_RQ + (nt*16 + l16)*40 + q16*8);
    const short8 br = *(const short8*)(relpad + RP_RK + (nt*16 + l16)*40 + q16*8);
    aU[nt] = __builtin_amdgcn_mfma_f32_16x16x32_bf16(aq, bq, aU[nt], 0, 0, 0);
    aV[nt] = __builtin_amdgcn_mfma_f32_16x16x32_bf16(ak, br, aV[nt], 0, 0, 0);
  }
}

static __device__ __forceinline__ void writeUV(unsigned short* sm, int w, int q16, int l16,
                                               const f32x4 aU[7], const f32x4 aV[7]){
  #pragma unroll
  for (int nt = 0; nt < 7; ++nt){
    const int d = nt*16 + l16;
    #pragma unroll
    for (int r = 0; r < 4; ++r){
      const int i = w*16 + q16*4 + r;
      if (i < HH){
        sm[A2_UL + i*116 + d] = f2u(aU[nt][r]);   // stride 116: q16 groups on
        sm[A2_VL + i*116 + d] = f2u(aV[nt][r]);   // disjoint bank spans
      }
    }
  }
}

// ---------------- kScore: MFMA scores -> BN2 stats, all in registers ----------------
__global__ __launch_bounds__(256) void kScore(const bf16* __restrict__ qkv,
                                              const unsigned short* __restrict__ relpad,
                                              const float* __restrict__ sc1, const float* __restrict__ sh1,
                                              float* __restrict__ psum, float* __restrict__ psq){
  const int b = blockIdx.x, g = blockIdx.y;
  __shared__ __align__(16) unsigned short sm[5120];   // qT/kT only (10 KB)
  __shared__ float red[6][4];
  const int t = threadIdx.x;
  const int lane = t & 63, w = t >> 6;
  const int q16 = lane >> 4, l16 = lane & 15;

  stageQK(sm, (const unsigned short*)qkv, sc1, sh1, b, g, t);
  __syncthreads();

  f32x4 aqk[4], aU[7], aV[7];
  #pragma unroll
  for (int nt = 0; nt < 4; ++nt) aqk[nt] = (f32x4){0.f,0.f,0.f,0.f};
  #pragma unroll
  for (int nt = 0; nt < 7; ++nt){ aU[nt] = (f32x4){0.f,0.f,0.f,0.f}; aV[nt] = (f32x4){0.f,0.f,0.f,0.f}; }
  scoreMFMA(sm, relpad, w, q16, l16, aqk, aU, aV);

  float s0=0.f,s1=0.f,s2=0.f,p0=0.f,p1=0.f,p2=0.f;
  #pragma unroll
  for (int nt = 0; nt < 4; ++nt){
    const int j = nt*16 + l16;
    #pragma unroll
    for (int r = 0; r < 4; ++r){
      const int i = w*16 + q16*4 + r;
      if (i < HH && j < HH){ float v = aqk[nt][r]; s0 += v; p0 += v*v; }
    }
  }
  #pragma unroll
  for (int nt = 0; nt < 7; ++nt){
    const int d = nt*16 + l16;
    #pragma unroll
    for (int r = 0; r < 4; ++r){
      const int row = w*16 + q16*4 + r;
      if (row < HH && (unsigned)(d - row) < (unsigned)HH){
        float u = aU[nt][r]; s1 += u; p1 += u*u;
        float v = aV[nt][r]; s2 += v; p2 += v*v;
      }
    }
  }
  float s[3] = {s0,s1,s2}, q2[3] = {p0,p1,p2};
  #pragma unroll
  for (int off = 32; off > 0; off >>= 1)
    #pragma unroll
    for (int m = 0; m < 3; ++m){ s[m]+=__shfl_down(s[m],off); q2[m]+=__shfl_down(q2[m],off); }
  if ((t & 63) == 0){
    #pragma unroll
    for (int m = 0; m < 3; ++m){ red[m][w] = s[m]; red[3+m][w] = q2[m]; }
  }
  __syncthreads();
  if (t < 6){
    float v = red[t][0]+red[t][1]+red[t][2]+red[t][3];
    int m = t % 3;
    int ch = m*8 + g;
    float* dstp = (t >= 3) ? psq : psum;
    atomicAdd(&dstp[(b & 7)*24 + ch], v);    // 8-slot spread
  }
}

__global__ void kF2(const float* __restrict__ psum, const float* __restrict__ psq,
                    const void* __restrict__ gs, const void* __restrict__ bs,
                    float* __restrict__ sc2, float* __restrict__ sh2,
                    const int* __restrict__ dflag){
  const bool f32 = (*dflag != 0);
  const int ch = threadIdx.x;
  if (ch < 24){
    float S = 0.f, Q = 0.f;
    for (int sl = 0; sl < 8; ++sl){ S += psum[sl*24 + ch]; Q += psq[sl*24 + ch]; }
    const float cnt = (float)BB * (float)(HH*HH);
    float mean = S / cnt;
    float var  = Q / cnt - mean*mean;
    float scale = ldin(gs, ch, f32) * rsqrtf(var + EPSV);
    sc2[ch] = scale; sh2[ch] = ldin(bs, ch, f32) - mean*scale;
  }
}

// ---------------- kAttn2: scores -> BN2 -> softmax -> PV (BN3 partials -> pst3) ----------------
__global__ __launch_bounds__(256) void kAttn2(const bf16* __restrict__ qkv,
                                              const unsigned short* __restrict__ relpad,
                                              const float* __restrict__ sc1, const float* __restrict__ sh1,
                                              const float* __restrict__ sc2, const float* __restrict__ sh2,
                                              bf16* __restrict__ outr,
                                              float* __restrict__ pst3){
  const int b = blockIdx.x, g = blockIdx.y;
  __shared__ __align__(16) unsigned short sm[A2_TOT];
  const int t = threadIdx.x;
  const int lane = t & 63, w = t >> 6;
  const int q16 = lane >> 4, l16 = lane & 15;

  // phase 1: q/k staging only (rel stays in global/L1)
  stageQK(sm, (const unsigned short*)qkv, sc1, sh1, b, g, t);
  __syncthreads();

  // phase 2: score MFMAs
  f32x4 aqk[4], aU[7], aV[7];
  #pragma unroll
  for (int nt = 0; nt < 4; ++nt) aqk[nt] = (f32x4){0.f,0.f,0.f,0.f};
  #pragma unroll
  for (int nt = 0; nt < 7; ++nt){ aU[nt] = (f32x4){0.f,0.f,0.f,0.f}; aV[nt] = (f32x4){0.f,0.f,0.f,0.f}; }
  scoreMFMA(sm, relpad, w, q16, l16, aqk, aU, aV);
  __syncthreads();

  // phase 3: Ul/Vl overlay (stride 116)
  writeUV(sm, w, q16, l16, aU, aV);
  __syncthreads();

  // phase 4: sim = BN2(qk)+BN2(qr)+BN2(kr), f16
  {
    const float scqk=sc2[g],    shqk=sh2[g];
    const float scqr=sc2[8+g],  shqr=sh2[8+g];
    const float sckr=sc2[16+g], shkr=sh2[16+g];
    _Float16* simh = (_Float16*)&sm[A2_SIM];
    #pragma unroll
    for (int nt = 0; nt < 4; ++nt){
      const int j = nt*16 + l16;
      #pragma unroll
      for (int r = 0; r < 4; ++r){
        const int i = w*16 + q16*4 + r;
        if (i < HH && j < HH){
          float qr = u2f(sm[A2_UL + i*116 + (i - j + 55)]);
          float kr = u2f(sm[A2_VL + j*116 + (j - i + 55)]);
          float sv_ = aqk[nt][r]*scqk + shqk + qr*scqr + shqr + kr*sckr + shkr;
          simh[i*60 + j] = (_Float16)sv_;
        }
      }
    }
  }
  __syncthreads();

  // phase 5: full zero of P/S' (12800u = 6400 dwords)
  for (int i = t; i < 6400; i += 256) ((unsigned int*)sm)[i] = 0u;
  __syncthreads();

  // phase 6: softmax rows -> P and gathered S'
  if (t < 224){
    const _Float16* simh = (const _Float16*)&sm[A2_SIM];
    const int r = t >> 2, l4 = t & 3;
    float pvv[14]; float mx = -1e30f;
    #pragma unroll
    for (int m = 0; m < 14; ++m){ pvv[m] = (float)simh[r*60 + l4 + 4*m]; mx = fmaxf(mx, pvv[m]); }
    mx = fmaxf(mx, __shfl_xor(mx, 1)); mx = fmaxf(mx, __shfl_xor(mx, 2));
    float smm = 0.f;
    #pragma unroll
    for (int m = 0; m < 14; ++m){ pvv[m] = __expf(pvv[m] - mx); smm += pvv[m]; }
    smm += __shfl_xor(smm, 1); smm += __shfl_xor(smm, 2);
    const float inv = 1.f / smm;
    #pragma unroll
    for (int m = 0; m < 14; ++m){
      const int j = l4 + 4*m;
      unsigned short pu = f2u(pvv[m]*inv);
      sm[A2_P  + r*72  + j]            = pu;
      sm[A2_SP + r*128 + (r - j + 55)] = pu;
    }
  }
  __syncthreads();

  // phase 7: PV in two c-halves (v staged into dead sim region; Rv read direct)
  f32x4 asv[4], asve[4];
  #pragma unroll
  for (int nt = 0; nt < 4; ++nt){ asv[nt] = (f32x4){0.f,0.f,0.f,0.f}; asve[nt] = (f32x4){0.f,0.f,0.f,0.f}; }
  const short8 ap0 = *(const short8*)&sm[A2_P + (w*16 + l16)*72 + q16*8];
  const short8 ap1 = *(const short8*)&sm[A2_P + (w*16 + l16)*72 + 32 + q16*8];
  short8 asp[4];
  #pragma unroll
  for (int kk = 0; kk < 4; ++kk)
    asp[kk] = *(const short8*)&sm[A2_SP + (w*16 + l16)*128 + kk*32 + q16*8];

  #pragma unroll
  for (int half = 0; half < 2; ++half){
    const unsigned short* vp = (const unsigned short*)qkv
        + ((size_t)b*OO + g*128 + 64 + half*32)*HH;
    for (int q = t; q < 448; q += 256){
      int c2 = q / 14, hq = q - c2*14;
      int o = g*128 + 64 + half*32 + c2;
      ushort4 u = *(const ushort4*)(vp + (size_t)c2*HH + hq*4);
      float s = sc1[o], hb = sh1[o];
      unsigned short* d = &sm[A2_VH + c2*72 + hq*4];
      d[0] = f2u(u2f(u.x)*s + hb);
      d[1] = f2u(u2f(u.y)*s + hb);
      d[2] = f2u(u2f(u.z)*s + hb);
      d[3] = f2u(u2f(u.w)*s + hb);
    }
    { int c2 = t >> 3, e = t & 7; sm[A2_VH + c2*72 + 56 + e] = 0; }
    __syncthreads();
    #pragma unroll
    for (int ntl = 0; ntl < 2; ++ntl){
      const int nt = half*2 + ntl;
      const short8 bv0 = *(const short8*)&sm[A2_VH + (ntl*16 + l16)*72 + q16*8];
      const short8 bv1 = *(const short8*)&sm[A2_VH + (ntl*16 + l16)*72 + 32 + q16*8];
      asv[nt] = __builtin_amdgcn_mfma_f32_16x16x32_bf16(ap0, bv0, asv[nt], 0, 0, 0);
      asv[nt] = __builtin_amdgcn_mfma_f32_16x16x32_bf16(ap1, bv1, asv[nt], 0, 0, 0);
      #pragma unroll
      for (int kk = 0; kk < 4; ++kk){
        const short8 br = *(const short8*)(relpad + RP_RV
            + (size_t)(half*32 + ntl*16 + l16)*136 + kk*32 + q16*8);
        asve[nt] = __builtin_amdgcn_mfma_f32_16x16x32_bf16(asp[kk], br, asve[nt], 0, 0, 0);
      }
    }
    __syncthreads();
  }

  // epilogue: C-write
  const int i0 = w*16 + q16*4;
  if (i0 < HH){
    unsigned short* op = (unsigned short*)outr + (size_t)b*OO*HH;
    #pragma unroll
    for (int nt = 0; nt < 4; ++nt){
      const int c = nt*16 + l16;
      const int och = (g*64 + c)*2;
      *(ushort4*)(op + (size_t)och*HH + i0) =
        make_ushort4(f2u(asv[nt][0]),  f2u(asv[nt][1]),  f2u(asv[nt][2]),  f2u(asv[nt][3]));
      *(ushort4*)(op + (size_t)(och+1)*HH + i0) =
        make_ushort4(f2u(asve[nt][0]), f2u(asve[nt][1]), f2u(asve[nt][2]), f2u(asve[nt][3]));
    }
  }

  // fused BN3 partial stats -> 64-slot-spread (14 contenders/addr)
  {
    float* fr = (float*)sm;
    const bool ivalid = (i0 < HH);
    #pragma unroll
    for (int nt = 0; nt < 4; ++nt){
      float ssv = 0.f, qsv = 0.f, ssve = 0.f, qsve = 0.f;
      if (ivalid){
        #pragma unroll
        for (int r = 0; r < 4; ++r){
          float a = asv[nt][r], e2 = asve[nt][r];
          ssv += a; qsv += a*a; ssve += e2; qsve += e2*e2;
        }
      }
      ssv  += __shfl_xor(ssv, 16);  ssv  += __shfl_xor(ssv, 32);
      qsv  += __shfl_xor(qsv, 16);  qsv  += __shfl_xor(qsv, 32);
      ssve += __shfl_xor(ssve, 16); ssve += __shfl_xor(ssve, 32);
      qsve += __shfl_xor(qsve, 16); qsve += __shfl_xor(qsve, 32);
      if (q16 == 0)
        *(f32x4*)&fr[(size_t)w*256 + (nt*16 + l16)*4] = (f32x4){ssv, qsv, ssve, qsve};
    }
    __syncthreads();
    float xv = fr[t] + fr[256 + t] + fr[512 + t] + fr[768 + t];
    atomicAdd(&pst3[(size_t)(b & 63)*2048 + g*256 + t], xv);
  }
}

// ---------------- fold BN3 64-slot partials -> scale/shift ----------------
__global__ __launch_bounds__(256) void kFin3(const float* __restrict__ pst3,
                                             const void* __restrict__ gamma, const void* __restrict__ beta,
                                             float* __restrict__ sc, float* __restrict__ sh,
                                             const int* __restrict__ dflag){
  const bool f32 = (*dflag != 0);
  const int g = blockIdx.x;      // 8 blocks
  const int t = threadIdx.x;
  float tot = 0.f;
  for (int s = 0; s < 64; ++s) tot += pst3[(size_t)s*2048 + g*256 + t];
  __shared__ float sd[256];
  const int v = t & 3, nt = t >> 6, l16v = (t >> 2) & 15;
  const int ol = (nt*16 + l16v)*2 + (v >> 1);
  sd[ol*2 + (v & 1)] = tot;
  __syncthreads();
  if (t < 128){
    float S = sd[t*2], Q = sd[t*2 + 1];
    const int ch = g*128 + t;
    const float cnt = (float)(BB*HH);
    float mean = S / cnt;
    float var  = Q / cnt - mean*mean;
    float scale = ldin(gamma, ch, f32) * rsqrtf(var + EPSV);
    sc[ch] = scale; sh[ch] = ldin(beta, ch, f32) - mean*scale;
  }
}

// ---------------- BN3 + pair-sum + transpose to (N,512,H,W), 4 p per block ----------------
__global__ __launch_bounds__(256) void kOut(const bf16* __restrict__ outr, const float* __restrict__ sc3,
                                            const float* __restrict__ sh3, void* __restrict__ out,
                                            const int* __restrict__ dflag){
  const bool f32 = (*dflag != 0);
  const int p0 = blockIdx.x, n = blockIdx.y;    // grid (128, 16)
  __shared__ float tile[4][HH][WW+1];           // 51072 B
  const unsigned short* ip = (const unsigned short*)outr;
  for (int idx = threadIdx.x; idx < 1568; idx += 256){   // 56 w x 4 pp x 7 h8
    int w = idx / 28, rem = idx - w*28;
    int pp = rem / 7, h8 = rem - pp*7;
    const int p = 4*p0 + pp;
    size_t base = ((size_t)((n*WW + w)*OO) + 2*p)*HH + h8*8;
    short8 ua = *(const short8*)(ip + base);
    short8 ub = *(const short8*)(ip + base + HH);
    float s0 = sc3[2*p], h0 = sh3[2*p], s1 = sc3[2*p+1], h1 = sh3[2*p+1];
    #pragma unroll
    for (int e = 0; e < 8; ++e)
      tile[pp][h8*8+e][w] = u2f((unsigned short)ua[e])*s0 + h0 + u2f((unsigned short)ub[e])*s1 + h1;
  }
  __syncthreads();
  for (int idx = threadIdx.x; idx < 3136; idx += 256){   // 4 pp x 56 h x 14 w4
    int pp = idx / 784, rem = idx - pp*784;
    int h = rem / 14, w4 = rem - h*14;
    const size_t obase = ((size_t)(n*512 + 4*p0 + pp))*HH*WW;
    float4 v = make_float4(tile[pp][h][w4*4], tile[pp][h][w4*4+1],
                           tile[pp][h][w4*4+2], tile[pp][h][w4*4+3]);
    if (f32){
      *(float4*)((float*)out + obase + (size_t)h*WW + w4*4) = v;
    } else {
      *(ushort4*)((unsigned short*)out + obase + (size_t)h*WW + w4*4) =
        make_ushort4(f2u(v.x), f2u(v.y), f2u(v.z), f2u(v.w));
    }
  }
}

extern "C" void kernel_launch(void* const* d_in, const int* in_sizes, int n_in,
                              void* d_out, int out_size, void* d_ws, size_t ws_size,
                              hipStream_t stream){
  (void)in_sizes; (void)n_in; (void)out_size; (void)ws_size;
  const void* x    = d_in[0];
  const void* wqkv = d_in[1];
  const void* rel  = d_in[2];
  const void* gq   = d_in[3];
  const void* bq   = d_in[4];
  const void* gs   = d_in[5];
  const void* bs   = d_in[6];
  const void* go   = d_in[7];
  const void* bo   = d_in[8];

  char* ws = (char*)d_ws;
  const size_t szA = (size_t)BB*OO*HH*2;   // 102,760,448 B
  bf16* xtk  = (bf16*)ws;                  // [B][H][C]  (dead after GEMM)
  bf16* outr = (bf16*)ws;                  // [B][O][H]  (reuses region A)
  unsigned short* wbf = (unsigned short*)(ws + (size_t)64*1024*1024);   // 1 MB
  bf16* qkv  = (bf16*)(ws + szA);          // [B][O][H]
  float* st  = (float*)(ws + 2*szA);
  float* sc1   = st;
  float* sh1   = st + 1024;
  float* sc3   = st + 2048;
  float* sh3   = st + 3072;
  float* sc2   = st + 4096;
  float* sh2   = st + 4128;
  int*   flag  = (int*)(st + 4160);
  // kDetect zeroes st[2048 .. 7424):
  float* psum   = st + 4352;               // BN2 [8][24]
  float* psq    = st + 4544;               // BN2 [8][24]
  unsigned short* relpad = (unsigned short*)(ws + 2*szA + 32768);  // 17664u, ends +68096
  float* pstG = (float*)(ws + 2*szA + 69632);   // 1 MB: pst1 [64][2048] + pst3 [64][2048]
  float* pst1 = pstG;
  float* pst3 = pstG + 131072;

  kDetect <<<1, 128, 0, stream>>>(x, st + 2048, flag);
  kPrep   <<<1, 256, 0, stream>>>(rel, relpad, flag);
  kWPrep  <<<2048, 256, 0, stream>>>(wqkv, wbf, pstG, flag);
  kTrans  <<<dim3(HH, 4, NN), 256, 0, stream>>>(x, xtk, flag);
  kGemmQKV<<<dim3(8, BB/2), 256, 0, stream>>>(wbf, xtk, qkv, pst1);
  kFin1   <<<8, 256, 0, stream>>>(pst1, gq, bq, sc1, sh1, flag);
  kScore  <<<dim3(BB, GG), 256, 0, stream>>>(qkv, relpad, sc1, sh1, psum, psq);
  kF2     <<<1, 64, 0, stream>>>(psum, psq, gs, bs, sc2, sh2, flag);
  kAttn2  <<<dim3(BB, GG), 256, 0, stream>>>(qkv, relpad, sc1, sh1, sc2, sh2, outr, pst3);
  kFin3   <<<8, 256, 0, stream>>>(pst3, go, bo, sc3, sh3, flag);
  kOut    <<<dim3(128, NN), 256, 0, stream>>>(outr, sc3, sh3, d_out, flag);
}

// Round 11
// 563.423 us; speedup vs baseline: 1.2436x; 1.0095x over previous
//
#include <hip/hip_runtime.h>
#include <hip/hip_bf16.h>

typedef __hip_bfloat16 bf16;
typedef __attribute__((ext_vector_type(8))) short short8;
typedef __attribute__((ext_vector_type(4))) float f32x4;

#define NN   16
#define CIN  512
#define HH   56
#define WW   56
#define BB   (NN*WW)     /* 896 */
#define OO   1024
#define GG   8
#define RL   111         /* 2K-1 */
#define EPSV 1e-5f

// ---- shared LDS layout for kAttn2 (ushort offsets) ----
#define A2_QT  0         /* qT  [64 rows h][40u] cols c0..31          */
#define A2_KT  2560      /* kT  [64][40u]   (inputs end 5120)         */
#define A2_UL  0         /* Ul [56 i][116u d] (stride 116: bank-clean)*/
#define A2_VL  6496      /* Vl [56][116u]     (end 12992)             */
#define A2_P   0         /* P  [64 i][72u j]   overlay after phase 4  */
#define A2_SP  4608      /* S' [56 rows][136u d] (end 12224; rows     */
                         /* 56-63 unallocated: reads there hit SIM/VL */
                         /* garbage -> only ivalid-discarded outputs) */
#define A2_SIM 12992     /* sim f16 [56][60]   (end 16352)            */
#define A2_VH  12992     /* v half [32 c][72u j] phase 7 (SIM dead)   */
#define A2_TOT 16352     /* 32704 B                                   */

// relpad (ws) ushort offsets
#define RP_RQ 0          /* [112][40]  4480u */
#define RP_RK 4480       /* [112][40]  4480u */
#define RP_RV 8960       /* [64][136]  8704u  (end 17664) */

static __device__ __forceinline__ float u2f(unsigned short u){
  union { unsigned int i; float f; } x; x.i = ((unsigned int)u) << 16; return x.f;
}
static __device__ __forceinline__ unsigned short f2u(float f){
  union { float f; unsigned int i; } x; x.f = f;
  unsigned int i = x.i;
  unsigned int r = i + 0x7FFFu + ((i >> 16) & 1u);   // RNE
  return (unsigned short)(r >> 16);
}
// HW packed f32x2 -> bf16x2 (RNE), lo -> bits[15:0], hi -> bits[31:16]
static __device__ __forceinline__ unsigned int pkbf(float lo, float hi){
  unsigned int r;
  asm("v_cvt_pk_bf16_f32 %0, %1, %2" : "=v"(r) : "v"(lo), "v"(hi));
  return r;
}
static __device__ __forceinline__ float ldin(const void* p, size_t i, bool f32){
  return f32 ? ((const float*)p)[i] : u2f(((const unsigned short*)p)[i]);
}

typedef __attribute__((address_space(3))) unsigned int lds_u32;
typedef __attribute__((address_space(1))) const unsigned int glb_u32;

// ---------------- dtype probe + BN2 partial-stat zeroing ----------------
__global__ void kDetect(const void* __restrict__ x, float* __restrict__ part, int* __restrict__ flag){
  const int t = threadIdx.x;     // 128 threads
  for (int i = t; i < 5376; i += 128) part[i] = 0.f;   // st[2048..7424)
  unsigned short u = ((const unsigned short*)x)[t];
  int e = (u >> 7) & 0xFF;
  int bad = (e < 100 || e > 140) ? 1 : 0;
  __shared__ int cnt;
  if (t == 0) cnt = 0;
  __syncthreads();
  if (bad) atomicAdd(&cnt, 1);
  __syncthreads();
  if (t == 0) *flag = (cnt > 16) ? 1 : 0;   // 1 => inputs are fp32
}

// ---------------- build padded/transposed rel images in ws (once) ----------------
__global__ __launch_bounds__(256) void kPrep(const void* __restrict__ rel, unsigned short* __restrict__ relpad,
                                             const int* __restrict__ dflag){
  const bool f32 = (*dflag != 0);
  const int t = threadIdx.x;
  for (int i = t; i < 8960; i += 256){          // RqT / RkT  [d][c]
    int reg = i / 4480, r = i - reg*4480;
    int d = r / 40, c = r - d*40;
    float v = (d < RL && c < 32) ? ldin(rel, (size_t)(reg*32 + c)*RL + d, f32) : 0.f;
    relpad[i] = f2u(v);
  }
  for (int i = t; i < 8704; i += 256){          // Rv [c][d]
    int c = i / 136, d = i - c*136;
    float v = (d < RL) ? ldin(rel, (size_t)(64 + c)*RL + d, f32) : 0.f;
    relpad[RP_RV + i] = f2u(v);
  }
}

// ---------------- pre-convert w_qkv to bf16 + zero pstG (once) ----------------
__global__ __launch_bounds__(256) void kWPrep(const void* __restrict__ w, unsigned short* __restrict__ wbf,
                                              float* __restrict__ pstG, const int* __restrict__ dflag){
  const bool f32 = (*dflag != 0);
  const size_t i = (size_t)blockIdx.x*256 + threadIdx.x;   // 2048*256 = 524288 = 1024*512
  wbf[i] = f2u(ldin(w, i, f32));
  if (blockIdx.x < 256){   // zero 256*256*4 = 262144 floats = pst1 + pst3 (1 MB)
    ((f32x4*)pstG)[(size_t)blockIdx.x*256 + threadIdx.x] = (f32x4){0.f,0.f,0.f,0.f};
  }
}

// ---------------- transpose x (N,C,H,W) -> xtk[b=(n*W+w)][h][c] ----------------
__global__ __launch_bounds__(256) void kTrans(const void* __restrict__ x, bf16* __restrict__ xtk,
                                              const int* __restrict__ dflag){
  const bool f32 = (*dflag != 0);
  const int h  = blockIdx.x;       // 56
  const int cg = blockIdx.y;       // 4 groups of 128 channels
  const int n  = blockIdx.z;       // 16
  __shared__ unsigned short tile[128][58];
  const size_t rbase = (((size_t)n*CIN + cg*128)*HH + h)*WW;
  if (f32){
    const float* xp = (const float*)x;
    for (int idx = threadIdx.x; idx < 128*14; idx += 256){
      int ci = idx / 14, w4 = idx - ci*14;
      float4 v = *(const float4*)(xp + rbase + (size_t)ci*HH*WW + w4*4);
      *(unsigned int*)&tile[ci][w4*4]     = pkbf(v.x, v.y);
      *(unsigned int*)&tile[ci][w4*4 + 2] = pkbf(v.z, v.w);
    }
  } else {
    const unsigned short* xp = (const unsigned short*)x;
    for (int idx = threadIdx.x; idx < 128*WW; idx += 256){
      int ci = idx / WW, w = idx - ci*WW;
      tile[ci][w] = xp[rbase + (size_t)ci*HH*WW + w];   // bf16 passthrough
    }
  }
  __syncthreads();
  unsigned short* dst = (unsigned short*)xtk;
  for (int idx = threadIdx.x; idx < WW*16; idx += 256){
    int w = idx >> 4, c8 = idx & 15;
    short8 o;
    #pragma unroll
    for (int e = 0; e < 8; ++e) o[e] = (short)tile[c8*8+e][w];
    *(short8*)(dst + ((size_t)(n*WW + w)*HH + h)*CIN + cg*128 + c8*8) = o;
  }
}

// ---------------- MFMA GEMM: qkv[b][o][h] = sum_c w[o][c] * xtk[b][h][c] ----------------
// B: 3-deep counted-vmcnt global_load_lds; A: register prefetch from L2-hot wbf.
__global__ __launch_bounds__(256) void kGemmQKV(const unsigned short* __restrict__ wbf,
                                                const bf16* __restrict__ xtk,
                                                bf16* __restrict__ qkv,
                                                float* __restrict__ pst1){
  // bijective XCD swizzle: each XCD gets 56 consecutive b-pairs x all 8 o-blocks
  const int id = blockIdx.x + (blockIdx.y << 3);      // grid (8,448)
  const int lb = (id & 7)*448 + (id >> 3);
  const int fo = lb & 7, fb = lb >> 3;
  const int o0 = fo * 128;
  const int b0 = fb * 2;
  const int t  = threadIdx.x;
  const int lane = t & 63, wv = t >> 6;
  const int q16 = lane >> 4, l16 = lane & 15;

  __shared__ __align__(16) unsigned short Bs[3][4096];   // [k8][128 cols][8]

  const int L1 = t, L2 = t + 256;
  const int k81 = L1 >> 7, j1 = L1 & 127;
  const int k82 = L2 >> 7, j2 = L2 & 127;
  const int je1 = (j1 < 112) ? j1 : 111;   // pad cols 112..127 (never consumed)
  const int je2 = (j2 < 112) ? j2 : 111;
  const int bs1 = (je1 >= 56), bs2 = (je2 >= 56);
  const unsigned short* pB1 = (const unsigned short*)xtk
      + ((size_t)(b0 + bs1)*HH + (je1 - 56*bs1))*CIN + k81*8;
  const unsigned short* pB2 = (const unsigned short*)xtk
      + ((size_t)(b0 + bs2)*HH + (je2 - 56*bs2))*CIN + k82*8;
  const size_t aofs0 = (size_t)(o0 + wv*32 + l16)*CIN + q16*8;
  const size_t aofs1 = aofs0 + (size_t)16*CIN;

  f32x4 acc[2][7];
  #pragma unroll
  for (int mt = 0; mt < 2; ++mt)
    #pragma unroll
    for (int nt = 0; nt < 7; ++nt) acc[mt][nt] = (f32x4){0.f,0.f,0.f,0.f};

#define GQ_STAGE(KK) do { \
    __builtin_amdgcn_global_load_lds((glb_u32*)(pB1 + (KK)*32), (lds_u32*)&Bs[(KK)%3][(size_t)L1*8], 16, 0, 0); \
    __builtin_amdgcn_global_load_lds((glb_u32*)(pB2 + (KK)*32), (lds_u32*)&Bs[(KK)%3][(size_t)L2*8], 16, 0, 0); \
  } while(0)

#define GQ_STEP(KK, WS) do { \
    asm volatile("s_waitcnt vmcnt(" WS ") lgkmcnt(0)" ::: "memory"); \
    __builtin_amdgcn_s_barrier(); \
    __builtin_amdgcn_sched_barrier(0); \
    if ((KK) <= 13) GQ_STAGE((KK)+2); \
    const short8 ca0 = a0, ca1 = a1; \
    if ((KK) < 15){ \
      a0 = *(const short8*)(wbf + aofs0 + ((KK)+1)*32); \
      a1 = *(const short8*)(wbf + aofs1 + ((KK)+1)*32); \
    } \
    const int bi_ = (KK)%3; \
    _Pragma("unroll") \
    for (int nt = 0; nt < 7; ++nt){ \
      const short8 bfv = *(const short8*)&Bs[bi_][(q16*128 + nt*16 + l16)*8]; \
      acc[0][nt] = __builtin_amdgcn_mfma_f32_16x16x32_bf16(ca0, bfv, acc[0][nt], 0, 0, 0); \
      acc[1][nt] = __builtin_amdgcn_mfma_f32_16x16x32_bf16(ca1, bfv, acc[1][nt], 0, 0, 0); \
    } } while(0)

  GQ_STAGE(0); GQ_STAGE(1);
  short8 a0 = *(const short8*)(wbf + aofs0);
  short8 a1 = *(const short8*)(wbf + aofs1);
  GQ_STEP(0,"4");  GQ_STEP(1,"4");  GQ_STEP(2,"4");  GQ_STEP(3,"4");
  GQ_STEP(4,"4");  GQ_STEP(5,"4");  GQ_STEP(6,"4");  GQ_STEP(7,"4");
  GQ_STEP(8,"4");  GQ_STEP(9,"4");  GQ_STEP(10,"4"); GQ_STEP(11,"4");
  GQ_STEP(12,"4"); GQ_STEP(13,"4"); GQ_STEP(14,"4"); GQ_STEP(15,"2");

#undef GQ_STEP
#undef GQ_STAGE

  // C-write (cvt_pk pairs; rows strided by HH)
  unsigned short* dst = (unsigned short*)qkv;
  #pragma unroll
  for (int nt = 0; nt < 7; ++nt){
    const int j  = nt*16 + l16;
    const int bs = (j >= 56);
    const int h  = j - 56*bs;
    #pragma unroll
    for (int mt = 0; mt < 2; ++mt){
      const int orow = o0 + wv*32 + mt*16 + q16*4;
      size_t base = ((size_t)(b0 + bs)*OO + orow)*HH + h;
      unsigned int p01 = pkbf(acc[mt][nt][0], acc[mt][nt][1]);
      unsigned int p23 = pkbf(acc[mt][nt][2], acc[mt][nt][3]);
      dst[base]              = (unsigned short)p01;
      dst[base + HH]         = (unsigned short)(p01 >> 16);
      dst[base + 2*(size_t)HH] = (unsigned short)p23;
      dst[base + 3*(size_t)HH] = (unsigned short)(p23 >> 16);
    }
  }

  // fused BN1 partial stats; LDS scratch (Bs reuse) -> 64-slot-spread atomics
  __syncthreads();               // all MFMA LDS reads done before Bs reuse
  float* fb32 = (float*)Bs;      // 256 floats
  #pragma unroll
  for (int mt = 0; mt < 2; ++mt)
    #pragma unroll
    for (int r = 0; r < 4; ++r){
      float s = 0.f, q = 0.f;
      #pragma unroll
      for (int nt = 0; nt < 7; ++nt){ float v = acc[mt][nt][r]; s += v; q += v*v; }
      s += __shfl_xor(s, 1); q += __shfl_xor(q, 1);
      s += __shfl_xor(s, 2); q += __shfl_xor(q, 2);
      s += __shfl_xor(s, 4); q += __shfl_xor(q, 4);
      s += __shfl_xor(s, 8); q += __shfl_xor(q, 8);
      if (l16 == 0){
        const int rl = wv*32 + mt*16 + q16*4 + r;   // [0,128)
        fb32[rl*2]     = s;
        fb32[rl*2 + 1] = q;
      }
    }
  __syncthreads();
  atomicAdd(&pst1[(size_t)(fb & 63)*2048 + fo*256 + t], fb32[t]);
}

// ---------------- fold BN1 64-slot partials -> scale/shift ----------------
__global__ __launch_bounds__(256) void kFin1(const float* __restrict__ pst1,
                                             const void* __restrict__ gamma, const void* __restrict__ beta,
                                             float* __restrict__ sc, float* __restrict__ sh,
                                             const int* __restrict__ dflag){
  const bool f32 = (*dflag != 0);
  const int fo = blockIdx.x;     // 8 blocks
  const int t = threadIdx.x;
  float tot = 0.f;
  for (int s = 0; s < 64; ++s) tot += pst1[(size_t)s*2048 + fo*256 + t];
  __shared__ float sd[256];
  sd[t] = tot;                   // index t = rl*2 + stat
  __syncthreads();
  if (t < 128){
    float S = sd[t*2], Q = sd[t*2 + 1];
    const int ch = fo*128 + t;
    const float cnt = (float)(BB*HH);
    float mean = S / cnt;
    float var  = Q / cnt - mean*mean;
    float scale = ldin(gamma, ch, f32) * rsqrtf(var + EPSV);
    sc[ch] = scale; sh[ch] = ldin(beta, ch, f32) - mean*scale;
  }
}

// ============ shared helpers ============
static __device__ __forceinline__ void stageQK(unsigned short* sm, const unsigned short* qkv,
                                               const float* __restrict__ sc1, const float* __restrict__ sh1,
                                               int b, int g, int t){
  const unsigned short* qp = qkv + (size_t)(b*OO + g*128)*HH;
  for (int q = t; q < 896; q += 256){           // q/k rows, ushort4
    int c = q / 14, hq = q - c*14;
    int o = g*128 + c;
    ushort4 u = *(const ushort4*)(qp + (size_t)c*HH + hq*4);
    float s = sc1[o], hb = sh1[o];
    int base = (c < 32 ? A2_QT : A2_KT) + (c & 31) + hq*160;
    unsigned int p01 = pkbf(u2f(u.x)*s + hb, u2f(u.y)*s + hb);
    unsigned int p23 = pkbf(u2f(u.z)*s + hb, u2f(u.w)*s + hb);
    sm[base]       = (unsigned short)p01;
    sm[base + 40]  = (unsigned short)(p01 >> 16);
    sm[base + 80]  = (unsigned short)p23;
    sm[base + 120] = (unsigned short)(p23 >> 16);
  }
  for (int i = t; i < 640; i += 256){           // zero rows 56..63 of qT/kT
    int a = i / 320, r = i - a*320;
    sm[(a ? A2_KT : A2_QT) + 2240 + r] = 0;
  }
}

static __device__ __forceinline__ void scoreMFMA(const unsigned short* sm,
                                                 const unsigned short* __restrict__ relpad,
                                                 int w, int q16, int l16,
                                                 f32x4 aqk[4], f32x4 aU[7], f32x4 aV[7]){
  const short8 aq = *(const short8*)&sm[A2_QT + (w*16 + l16)*40 + q16*8];
  const short8 ak = *(const short8*)&sm[A2_KT + (w*16 + l16)*40 + q16*8];
  #pragma unroll
  for (int nt = 0; nt < 4; ++nt){
    const short8 bk = *(const short8*)&sm[A2_KT + (nt*16 + l16)*40 + q16*8];
    aqk[nt] = __builtin_amdgcn_mfma_f32_16x16x32_bf16(aq, bk, aqk[nt], 0, 0, 0);
  }
  #pragma unroll
  for (int nt = 0; nt < 7; ++nt){
    const short8 bq = *(const short8*)(relpad + RP_RQ + (nt*16 + l16)*40 + q16*8);
    const short8 br = *(const short8*)(relpad + RP_RK + (nt*16 + l16)*40 + q16*8);
    aU[nt] = __builtin_amdgcn_mfma_f32_16x16x32_bf16(aq, bq, aU[nt], 0, 0, 0);
    aV[nt] = __builtin_amdgcn_mfma_f32_16x16x32_bf16(ak, br, aV[nt], 0, 0, 0);
  }
}

static __device__ __forceinline__ void writeUV(unsigned short* sm, int w, int q16, int l16,
                                               const f32x4 aU[7], const f32x4 aV[7]){
  const int i0w = w*16 + q16*4;
  if (i0w >= HH) return;          // quad-uniform: rows i0w..i0w+3 all <56 or all >=56
  #pragma unroll
  for (int nt = 0; nt < 7; ++nt){
    const int d = nt*16 + l16;
    const int ub = A2_UL + i0w*116 + d;
    const int vb = A2_VL + i0w*116 + d;
    unsigned int u01 = pkbf(aU[nt][0], aU[nt][1]);
    unsigned int u23 = pkbf(aU[nt][2], aU[nt][3]);
    unsigned int v01 = pkbf(aV[nt][0], aV[nt][1]);
    unsigned int v23 = pkbf(aV[nt][2], aV[nt][3]);
    sm[ub]         = (unsigned short)u01;
    sm[ub + 116]   = (unsigned short)(u01 >> 16);
    sm[ub + 232]   = (unsigned short)u23;
    sm[ub + 348]   = (unsigned short)(u23 >> 16);
    sm[vb]         = (unsigned short)v01;
    sm[vb + 116]   = (unsigned short)(v01 >> 16);
    sm[vb + 232]   = (unsigned short)v23;
    sm[vb + 348]   = (unsigned short)(v23 >> 16);
  }
}

// ---------------- kScore: MFMA scores -> BN2 stats, all in registers ----------------
__global__ __launch_bounds__(256) void kScore(const bf16* __restrict__ qkv,
                                              const unsigned short* __restrict__ relpad,
                                              const float* __restrict__ sc1, const float* __restrict__ sh1,
                                              float* __restrict__ psum, float* __restrict__ psq){
  const int b = blockIdx.x, g = blockIdx.y;
  __shared__ __align__(16) unsigned short sm[5120];   // qT/kT only (10 KB)
  __shared__ float red[6][4];
  const int t = threadIdx.x;
  const int lane = t & 63, w = t >> 6;
  const int q16 = lane >> 4, l16 = lane & 15;

  stageQK(sm, (const unsigned short*)qkv, sc1, sh1, b, g, t);
  __syncthreads();

  f32x4 aqk[4], aU[7], aV[7];
  #pragma unroll
  for (int nt = 0; nt < 4; ++nt) aqk[nt] = (f32x4){0.f,0.f,0.f,0.f};
  #pragma unroll
  for (int nt = 0; nt < 7; ++nt){ aU[nt] = (f32x4){0.f,0.f,0.f,0.f}; aV[nt] = (f32x4){0.f,0.f,0.f,0.f}; }
  scoreMFMA(sm, relpad, w, q16, l16, aqk, aU, aV);

  float s0=0.f,s1=0.f,s2=0.f,p0=0.f,p1=0.f,p2=0.f;
  #pragma unroll
  for (int nt = 0; nt < 4; ++nt){
    const int j = nt*16 + l16;
    #pragma unroll
    for (int r = 0; r < 4; ++r){
      const int i = w*16 + q16*4 + r;
      if (i < HH && j < HH){ float v = aqk[nt][r]; s0 += v; p0 += v*v; }
    }
  }
  #pragma unroll
  for (int nt = 0; nt < 7; ++nt){
    const int d = nt*16 + l16;
    #pragma unroll
    for (int r = 0; r < 4; ++r){
      const int row = w*16 + q16*4 + r;
      if (row < HH && (unsigned)(d - row) < (unsigned)HH){
        float u = aU[nt][r]; s1 += u; p1 += u*u;
        float v = aV[nt][r]; s2 += v; p2 += v*v;
      }
    }
  }
  float s[3] = {s0,s1,s2}, q2[3] = {p0,p1,p2};
  #pragma unroll
  for (int off = 32; off > 0; off >>= 1)
    #pragma unroll
    for (int m = 0; m < 3; ++m){ s[m]+=__shfl_down(s[m],off); q2[m]+=__shfl_down(q2[m],off); }
  if ((t & 63) == 0){
    #pragma unroll
    for (int m = 0; m < 3; ++m){ red[m][w] = s[m]; red[3+m][w] = q2[m]; }
  }
  __syncthreads();
  if (t < 6){
    float v = red[t][0]+red[t][1]+red[t][2]+red[t][3];
    int m = t % 3;
    int ch = m*8 + g;
    float* dstp = (t >= 3) ? psq : psum;
    atomicAdd(&dstp[(b & 7)*24 + ch], v);    // 8-slot spread
  }
}

__global__ void kF2(const float* __restrict__ psum, const float* __restrict__ psq,
                    const void* __restrict__ gs, const void* __restrict__ bs,
                    float* __restrict__ sc2, float* __restrict__ sh2,
                    const int* __restrict__ dflag){
  const bool f32 = (*dflag != 0);
  const int ch = threadIdx.x;
  if (ch < 24){
    float S = 0.f, Q = 0.f;
    for (int sl = 0; sl < 8; ++sl){ S += psum[sl*24 + ch]; Q += psq[sl*24 + ch]; }
    const float cnt = (float)BB * (float)(HH*HH);
    float mean = S / cnt;
    float var  = Q / cnt - mean*mean;
    float scale = ldin(gs, ch, f32) * rsqrtf(var + EPSV);
    sc2[ch] = scale; sh2[ch] = ldin(bs, ch, f32) - mean*scale;
  }
}

// ---------------- kAttn2: scores -> BN2 -> softmax -> PV (BN3 partials -> pst3) ----------------
__global__ __launch_bounds__(256) void kAttn2(const bf16* __restrict__ qkv,
                                              const unsigned short* __restrict__ relpad,
                                              const float* __restrict__ sc1, const float* __restrict__ sh1,
                                              const float* __restrict__ sc2, const float* __restrict__ sh2,
                                              bf16* __restrict__ outr,
                                              float* __restrict__ pst3){
  const int b = blockIdx.x, g = blockIdx.y;
  __shared__ __align__(16) unsigned short sm[A2_TOT];
  const int t = threadIdx.x;
  const int lane = t & 63, w = t >> 6;
  const int q16 = lane >> 4, l16 = lane & 15;

  // phase 1: q/k staging only (rel stays in global/L1)
  stageQK(sm, (const unsigned short*)qkv, sc1, sh1, b, g, t);
  __syncthreads();

  // phase 2: score MFMAs
  f32x4 aqk[4], aU[7], aV[7];
  #pragma unroll
  for (int nt = 0; nt < 4; ++nt) aqk[nt] = (f32x4){0.f,0.f,0.f,0.f};
  #pragma unroll
  for (int nt = 0; nt < 7; ++nt){ aU[nt] = (f32x4){0.f,0.f,0.f,0.f}; aV[nt] = (f32x4){0.f,0.f,0.f,0.f}; }
  scoreMFMA(sm, relpad, w, q16, l16, aqk, aU, aV);
  __syncthreads();

  // phase 3: Ul/Vl overlay (stride 116)
  writeUV(sm, w, q16, l16, aU, aV);
  __syncthreads();

  // phase 4: sim = BN2(qk)+BN2(qr)+BN2(kr), f16
  {
    const float scqk=sc2[g],    shqk=sh2[g];
    const float scqr=sc2[8+g],  shqr=sh2[8+g];
    const float sckr=sc2[16+g], shkr=sh2[16+g];
    _Float16* simh = (_Float16*)&sm[A2_SIM];
    #pragma unroll
    for (int nt = 0; nt < 4; ++nt){
      const int j = nt*16 + l16;
      #pragma unroll
      for (int r = 0; r < 4; ++r){
        const int i = w*16 + q16*4 + r;
        if (i < HH && j < HH){
          float qr = u2f(sm[A2_UL + i*116 + (i - j + 55)]);
          float kr = u2f(sm[A2_VL + j*116 + (j - i + 55)]);
          float sv_ = aqk[nt][r]*scqk + shqk + qr*scqr + shqr + kr*sckr + shkr;
          simh[i*60 + j] = (_Float16)sv_;
        }
      }
    }
  }
  __syncthreads();

  // phase 5: zero P (64 rows) + S' rows 0..55  (12224u = 6112 dwords)
  for (int i = t; i < 6112; i += 256) ((unsigned int*)sm)[i] = 0u;
  __syncthreads();

  // phase 6: softmax rows -> P and gathered S' (cvt_pk pairs m,m+1)
  if (t < 224){
    const _Float16* simh = (const _Float16*)&sm[A2_SIM];
    const int r = t >> 2, l4 = t & 3;
    float pvv[14]; float mx = -1e30f;
    #pragma unroll
    for (int m = 0; m < 14; ++m){ pvv[m] = (float)simh[r*60 + l4 + 4*m]; mx = fmaxf(mx, pvv[m]); }
    mx = fmaxf(mx, __shfl_xor(mx, 1)); mx = fmaxf(mx, __shfl_xor(mx, 2));
    float smm = 0.f;
    #pragma unroll
    for (int m = 0; m < 14; ++m){ pvv[m] = __expf(pvv[m] - mx); smm += pvv[m]; }
    smm += __shfl_xor(smm, 1); smm += __shfl_xor(smm, 2);
    const float inv = 1.f / smm;
    #pragma unroll
    for (int e = 0; e < 7; ++e){
      const int j0 = l4 + 8*e;                  // pair (j0, j0+4)
      unsigned int pk = pkbf(pvv[2*e]*inv, pvv[2*e+1]*inv);
      sm[A2_P  + r*72  + j0]               = (unsigned short)pk;
      sm[A2_P  + r*72  + j0 + 4]           = (unsigned short)(pk >> 16);
      sm[A2_SP + r*136 + (r - j0 + 55)]    = (unsigned short)pk;
      sm[A2_SP + r*136 + (r - j0 + 51)]    = (unsigned short)(pk >> 16);
    }
  }
  __syncthreads();

  // phase 7: PV in two c-halves (v staged into dead sim region; Rv read direct)
  f32x4 asv[4], asve[4];
  #pragma unroll
  for (int nt = 0; nt < 4; ++nt){ asv[nt] = (f32x4){0.f,0.f,0.f,0.f}; asve[nt] = (f32x4){0.f,0.f,0.f,0.f}; }
  const short8 ap0 = *(const short8*)&sm[A2_P + (w*16 + l16)*72 + q16*8];
  const short8 ap1 = *(const short8*)&sm[A2_P + (w*16 + l16)*72 + 32 + q16*8];
  short8 asp[4];    // rows >=56 read past SP into SIM/VL leftovers: finite garbage,
                    // affects only D rows 8-15 of wave 3 = ivalid-discarded outputs
  #pragma unroll
  for (int kk = 0; kk < 4; ++kk)
    asp[kk] = *(const short8*)&sm[A2_SP + (w*16 + l16)*136 + kk*32 + q16*8];

  #pragma unroll
  for (int half = 0; half < 2; ++half){
    const unsigned short* vp = (const unsigned short*)qkv
        + ((size_t)b*OO + g*128 + 64 + half*32)*HH;
    for (int q = t; q < 448; q += 256){
      int c2 = q / 14, hq = q - c2*14;
      int o = g*128 + 64 + half*32 + c2;
      ushort4 u = *(const ushort4*)(vp + (size_t)c2*HH + hq*4);
      float s = sc1[o], hb = sh1[o];
      const int off = A2_VH + c2*72 + hq*4;     // even -> u32-aligned
      *(unsigned int*)&sm[off]     = pkbf(u2f(u.x)*s + hb, u2f(u.y)*s + hb);
      *(unsigned int*)&sm[off + 2] = pkbf(u2f(u.z)*s + hb, u2f(u.w)*s + hb);
    }
    { int c2 = t >> 3, e = t & 7; sm[A2_VH + c2*72 + 56 + e] = 0; }
    __syncthreads();
    #pragma unroll
    for (int ntl = 0; ntl < 2; ++ntl){
      const int nt = half*2 + ntl;
      const short8 bv0 = *(const short8*)&sm[A2_VH + (ntl*16 + l16)*72 + q16*8];
      const short8 bv1 = *(const short8*)&sm[A2_VH + (ntl*16 + l16)*72 + 32 + q16*8];
      asv[nt] = __builtin_amdgcn_mfma_f32_16x16x32_bf16(ap0, bv0, asv[nt], 0, 0, 0);
      asv[nt] = __builtin_amdgcn_mfma_f32_16x16x32_bf16(ap1, bv1, asv[nt], 0, 0, 0);
      #pragma unroll
      for (int kk = 0; kk < 4; ++kk){
        const short8 br = *(const short8*)(relpad + RP_RV
            + (size_t)(half*32 + ntl*16 + l16)*136 + kk*32 + q16*8);
        asve[nt] = __builtin_amdgcn_mfma_f32_16x16x32_bf16(asp[kk], br, asve[nt], 0, 0, 0);
      }
    }
    __syncthreads();
  }

  // epilogue: C-write (cvt_pk -> uint2, 8B-aligned)
  const int i0 = w*16 + q16*4;
  if (i0 < HH){
    unsigned short* op = (unsigned short*)outr + (size_t)b*OO*HH;
    #pragma unroll
    for (int nt = 0; nt < 4; ++nt){
      const int c = nt*16 + l16;
      const int och = (g*64 + c)*2;
      uint2 wa, wb;
      wa.x = pkbf(asv[nt][0],  asv[nt][1]);  wa.y = pkbf(asv[nt][2],  asv[nt][3]);
      wb.x = pkbf(asve[nt][0], asve[nt][1]); wb.y = pkbf(asve[nt][2], asve[nt][3]);
      *(uint2*)(op + (size_t)och*HH + i0)     = wa;
      *(uint2*)(op + (size_t)(och+1)*HH + i0) = wb;
    }
  }

  // fused BN3 partial stats -> 64-slot-spread (14 contenders/addr)
  {
    float* fr = (float*)sm;
    const bool ivalid = (i0 < HH);
    #pragma unroll
    for (int nt = 0; nt < 4; ++nt){
      float ssv = 0.f, qsv = 0.f, ssve = 0.f, qsve = 0.f;
      if (ivalid){
        #pragma unroll
        for (int r = 0; r < 4; ++r){
          float a = asv[nt][r], e2 = asve[nt][r];
          ssv += a; qsv += a*a; ssve += e2; qsve += e2*e2;
        }
      }
      ssv  += __shfl_xor(ssv, 16);  ssv  += __shfl_xor(ssv, 32);
      qsv  += __shfl_xor(qsv, 16);  qsv  += __shfl_xor(qsv, 32);
      ssve += __shfl_xor(ssve, 16); ssve += __shfl_xor(ssve, 32);
      qsve += __shfl_xor(qsve, 16); qsve += __shfl_xor(qsve, 32);
      if (q16 == 0)
        *(f32x4*)&fr[(size_t)w*256 + (nt*16 + l16)*4] = (f32x4){ssv, qsv, ssve, qsve};
    }
    __syncthreads();
    float xv = fr[t] + fr[256 + t] + fr[512 + t] + fr[768 + t];
    atomicAdd(&pst3[(size_t)(b & 63)*2048 + g*256 + t], xv);
  }
}

// ---------------- fold BN3 64-slot partials -> scale/shift ----------------
__global__ __launch_bounds__(256) void kFin3(const float* __restrict__ pst3,
                                             const void* __restrict__ gamma, const void* __restrict__ beta,
                                             float* __restrict__ sc, float* __restrict__ sh,
                                             const int* __restrict__ dflag){
  const bool f32 = (*dflag != 0);
  const int g = blockIdx.x;      // 8 blocks
  const int t = threadIdx.x;
  float tot = 0.f;
  for (int s = 0; s < 64; ++s) tot += pst3[(size_t)s*2048 + g*256 + t];
  __shared__ float sd[256];
  const int v = t & 3, nt = t >> 6, l16v = (t >> 2) & 15;
  const int ol = (nt*16 + l16v)*2 + (v >> 1);
  sd[ol*2 + (v & 1)] = tot;
  __syncthreads();
  if (t < 128){
    float S = sd[t*2], Q = sd[t*2 + 1];
    const int ch = g*128 + t;
    const float cnt = (float)(BB*HH);
    float mean = S / cnt;
    float var  = Q / cnt - mean*mean;
    float scale = ldin(gamma, ch, f32) * rsqrtf(var + EPSV);
    sc[ch] = scale; sh[ch] = ldin(beta, ch, f32) - mean*scale;
  }
}

// ---------------- BN3 + pair-sum + transpose to (N,512,H,W), 4 p per block ----------------
__global__ __launch_bounds__(256) void kOut(const bf16* __restrict__ outr, const float* __restrict__ sc3,
                                            const float* __restrict__ sh3, void* __restrict__ out,
                                            const int* __restrict__ dflag){
  const bool f32 = (*dflag != 0);
  const int p0 = blockIdx.x, n = blockIdx.y;    // grid (128, 16)
  __shared__ float tile[4][HH][WW+1];           // 51072 B
  const unsigned short* ip = (const unsigned short*)outr;
  for (int idx = threadIdx.x; idx < 1568; idx += 256){   // 56 w x 4 pp x 7 h8
    int w = idx / 28, rem = idx - w*28;
    int pp = rem / 7, h8 = rem - pp*7;
    const int p = 4*p0 + pp;
    size_t base = ((size_t)((n*WW + w)*OO) + 2*p)*HH + h8*8;
    short8 ua = *(const short8*)(ip + base);
    short8 ub = *(const short8*)(ip + base + HH);
    float s0 = sc3[2*p], h0 = sh3[2*p], s1 = sc3[2*p+1], h1 = sh3[2*p+1];
    #pragma unroll
    for (int e = 0; e < 8; ++e)
      tile[pp][h8*8+e][w] = u2f((unsigned short)ua[e])*s0 + h0 + u2f((unsigned short)ub[e])*s1 + h1;
  }
  __syncthreads();
  for (int idx = threadIdx.x; idx < 3136; idx += 256){   // 4 pp x 56 h x 14 w4
    int pp = idx / 784, rem = idx - pp*784;
    int h = rem / 14, w4 = rem - h*14;
    const size_t obase = ((size_t)(n*512 + 4*p0 + pp))*HH*WW;
    float v0 = tile[pp][h][w4*4],   v1 = tile[pp][h][w4*4+1];
    float v2 = tile[pp][h][w4*4+2], v3 = tile[pp][h][w4*4+3];
    if (f32){
      *(float4*)((float*)out + obase + (size_t)h*WW + w4*4) = make_float4(v0,v1,v2,v3);
    } else {
      uint2 wv2; wv2.x = pkbf(v0, v1); wv2.y = pkbf(v2, v3);
      *(uint2*)((unsigned short*)out + obase + (size_t)h*WW + w4*4) = wv2;
    }
  }
}

extern "C" void kernel_launch(void* const* d_in, const int* in_sizes, int n_in,
                              void* d_out, int out_size, void* d_ws, size_t ws_size,
                              hipStream_t stream){
  (void)in_sizes; (void)n_in; (void)out_size; (void)ws_size;
  const void* x    = d_in[0];
  const void* wqkv = d_in[1];
  const void* rel  = d_in[2];
  const void* gq   = d_in[3];
  const void* bq   = d_in[4];
  const void* gs   = d_in[5];
  const void* bs   = d_in[6];
  const void* go   = d_in[7];
  const void* bo   = d_in[8];

  char* ws = (char*)d_ws;
  const size_t szA = (size_t)BB*OO*HH*2;   // 102,760,448 B
  bf16* xtk  = (bf16*)ws;                  // [B][H][C]  (dead after GEMM)
  bf16* outr = (bf16*)ws;                  // [B][O][H]  (reuses region A)
  unsigned short* wbf = (unsigned short*)(ws + (size_t)64*1024*1024);   // 1 MB
  bf16* qkv  = (bf16*)(ws + szA);          // [B][O][H]
  float* st  = (float*)(ws + 2*szA);
  float* sc1   = st;
  float* sh1   = st + 1024;
  float* sc3   = st + 2048;
  float* sh3   = st + 3072;
  float* sc2   = st + 4096;
  float* sh2   = st + 4128;
  int*   flag  = (int*)(st + 4160);
  // kDetect zeroes st[2048 .. 7424):
  float* psum   = st + 4352;               // BN2 [8][24]
  float* psq    = st + 4544;               // BN2 [8][24]
  unsigned short* relpad = (unsigned short*)(ws + 2*szA + 32768);  // 17664u, ends +68096
  float* pstG = (float*)(ws + 2*szA + 69632);   // 1 MB: pst1 [64][2048] + pst3 [64][2048]
  float* pst1 = pstG;
  float* pst3 = pstG + 131072;

  kDetect <<<1, 128, 0, stream>>>(x, st + 2048, flag);
  kPrep   <<<1, 256, 0, stream>>>(rel, relpad, flag);
  kWPrep  <<<2048, 256, 0, stream>>>(wqkv, wbf, pstG, flag);
  kTrans  <<<dim3(HH, 4, NN), 256, 0, stream>>>(x, xtk, flag);
  kGemmQKV<<<dim3(8, BB/2), 256, 0, stream>>>(wbf, xtk, qkv, pst1);
  kFin1   <<<8, 256, 0, stream>>>(pst1, gq, bq, sc1, sh1, flag);
  kScore  <<<dim3(BB, GG), 256, 0, stream>>>(qkv, relpad, sc1, sh1, psum, psq);
  kF2     <<<1, 64, 0, stream>>>(psum, psq, gs, bs, sc2, sh2, flag);
  kAttn2  <<<dim3(BB, GG), 256, 0, stream>>>(qkv, relpad, sc1, sh1, sc2, sh2, outr, pst3);
  kFin3   <<<8, 256, 0, stream>>>(pst3, go, bo, sc3, sh3, flag);
  kOut    <<<dim3(128, NN), 256, 0, stream>>>(outr, sc3, sh3, d_out, flag);
}